// Round 1
// baseline (2633.769 us; speedup 1.0000x reference)
//
#include <hip/hip_runtime.h>

#define G_   128
#define S_   32
#define N_   32
#define D_   128
#define T_   (G_*S_*N_)    // 131072
#define TO_  (G_*N_)       // 4096
#define E_   1048576
#define EO_  16384
#define HD_  32
#define NTASK_ 10

// ---------------- CSR build ----------------
__global__ void k_hist(const int* __restrict__ dst, int* __restrict__ deg, int n) {
    int e = blockIdx.x * 256 + threadIdx.x;
    if (e < n) atomicAdd(&deg[dst[e]], 1);
}

__global__ void k_scan1(const int* __restrict__ deg, int* __restrict__ incl, int* __restrict__ bsum, int n) {
    __shared__ int tmp[256];
    int i = blockIdx.x * 256 + threadIdx.x;
    int v = (i < n) ? deg[i] : 0;
    tmp[threadIdx.x] = v;
    __syncthreads();
    for (int off = 1; off < 256; off <<= 1) {
        int t = (threadIdx.x >= off) ? tmp[threadIdx.x - off] : 0;
        __syncthreads();
        tmp[threadIdx.x] += t;
        __syncthreads();
    }
    if (i < n) incl[i] = tmp[threadIdx.x];
    if (threadIdx.x == 255) bsum[blockIdx.x] = tmp[255];
}

__global__ void k_scan2(const int* __restrict__ bsum, int* __restrict__ bexcl, int nb) {
    __shared__ int tmp[512];
    int t = threadIdx.x;
    int v = (t < nb) ? bsum[t] : 0;
    tmp[t] = v;
    __syncthreads();
    for (int off = 1; off < 512; off <<= 1) {
        int u = (t >= off) ? tmp[t - off] : 0;
        __syncthreads();
        tmp[t] += u;
        __syncthreads();
    }
    if (t < nb) bexcl[t] = tmp[t] - v;
}

__global__ void k_scan3(const int* __restrict__ incl, const int* __restrict__ bexcl, int* __restrict__ rowptr, int n) {
    int i = blockIdx.x * 256 + threadIdx.x;
    if (i < n) rowptr[i + 1] = incl[i] + bexcl[blockIdx.x];
    if (i == 0) rowptr[0] = 0;
}

__global__ void k_copyint(const int* __restrict__ a, int* __restrict__ b, int n) {
    int i = blockIdx.x * 256 + threadIdx.x;
    if (i < n) b[i] = a[i];
}

__global__ void k_fill(const int* __restrict__ src, const int* __restrict__ dst,
                       int* __restrict__ cursor, int* __restrict__ colsrc, int n) {
    int e = blockIdx.x * 256 + threadIdx.x;
    if (e < n) {
        int pos = atomicAdd(&cursor[dst[e]], 1);
        colsrc[pos] = src[e];
    }
}

// ---------------- fused GraphConv + BN-stats ----------------
// out = xin @ Wr + (CSR-gathered sum of xin) @ Wn + bias ; also column sum/sumsq partials.
// 32 rows x 128 cols per block; 256 threads; 4x4 register tile per thread.
__global__ __launch_bounds__(256) void k_conv(
    const float* __restrict__ xin, const int* __restrict__ rowptr, const int* __restrict__ colsrc,
    const float* __restrict__ Wr, const float* __restrict__ Wn, const float* __restrict__ bias,
    float* __restrict__ hpre, float* __restrict__ colsum, float* __restrict__ colsq)
{
    __shared__ float xs[32][132];
    __shared__ float as[32][132];
    __shared__ float wrs[32][128];
    __shared__ float wns[32][128];
    __shared__ float csum[128];
    __shared__ float csq[128];
    const int tid = threadIdx.x;
    const int row0 = blockIdx.x * 32;
    if (tid < 128) { csum[tid] = 0.f; csq[tid] = 0.f; }
    // stage x tile (coalesced float4)
    for (int i = tid; i < 32 * 32; i += 256) {
        int r = i >> 5, c4 = (i & 31) * 4;
        *(float4*)&xs[r][c4] = *(const float4*)&xin[(size_t)(row0 + r) * 128 + c4];
    }
    // fused CSR gather of neighbor sums straight into LDS (no global agg round-trip)
    {
        int grp = tid >> 5, lane = tid & 31;
        for (int rr = grp; rr < 32; rr += 8) {
            int node = row0 + rr;
            int e0 = rowptr[node], e1 = rowptr[node + 1];
            float4 acc = make_float4(0.f, 0.f, 0.f, 0.f);
            for (int e = e0; e < e1; ++e) {
                int s = colsrc[e];
                float4 v = *(const float4*)&xin[(size_t)s * 128 + lane * 4];
                acc.x += v.x; acc.y += v.y; acc.z += v.z; acc.w += v.w;
            }
            *(float4*)&as[rr][lane * 4] = acc;
        }
    }
    const int cg = tid & 31, rg = tid >> 5;
    float acc[4][4];
    #pragma unroll
    for (int r = 0; r < 4; ++r)
        #pragma unroll
        for (int c = 0; c < 4; ++c) acc[r][c] = 0.f;
    for (int kc = 0; kc < 4; ++kc) {
        __syncthreads();   // covers initial staging (kc=0) and protects weight chunk reuse
        for (int i = tid; i < 32 * 32; i += 256) {
            int k = i >> 5, c4 = (i & 31) * 4;
            *(float4*)&wrs[k][c4] = *(const float4*)&Wr[(kc * 32 + k) * 128 + c4];
            *(float4*)&wns[k][c4] = *(const float4*)&Wn[(kc * 32 + k) * 128 + c4];
        }
        __syncthreads();
        #pragma unroll
        for (int k4 = 0; k4 < 8; ++k4) {
            float4 xv[4], av[4];
            #pragma unroll
            for (int r = 0; r < 4; ++r) {
                xv[r] = *(float4*)&xs[rg * 4 + r][kc * 32 + k4 * 4];
                av[r] = *(float4*)&as[rg * 4 + r][kc * 32 + k4 * 4];
            }
            #pragma unroll
            for (int kk = 0; kk < 4; ++kk) {
                float4 w1 = *(float4*)&wrs[k4 * 4 + kk][cg * 4];
                float4 w2 = *(float4*)&wns[k4 * 4 + kk][cg * 4];
                #pragma unroll
                for (int r = 0; r < 4; ++r) {
                    float xk = (&xv[r].x)[kk];
                    float ak = (&av[r].x)[kk];
                    acc[r][0] += xk * w1.x + ak * w2.x;
                    acc[r][1] += xk * w1.y + ak * w2.y;
                    acc[r][2] += xk * w1.z + ak * w2.z;
                    acc[r][3] += xk * w1.w + ak * w2.w;
                }
            }
        }
    }
    const float4 b4 = *(const float4*)&bias[cg * 4];
    float s0=0,s1=0,s2=0,s3=0,q0=0,q1=0,q2=0,q3=0;
    #pragma unroll
    for (int r = 0; r < 4; ++r) {
        float4 o;
        o.x = acc[r][0] + b4.x; o.y = acc[r][1] + b4.y;
        o.z = acc[r][2] + b4.z; o.w = acc[r][3] + b4.w;
        *(float4*)&hpre[(size_t)(row0 + rg * 4 + r) * 128 + cg * 4] = o;
        s0 += o.x; s1 += o.y; s2 += o.z; s3 += o.w;
        q0 += o.x*o.x; q1 += o.y*o.y; q2 += o.z*o.z; q3 += o.w*o.w;
    }
    atomicAdd(&csum[cg*4+0], s0); atomicAdd(&csum[cg*4+1], s1);
    atomicAdd(&csum[cg*4+2], s2); atomicAdd(&csum[cg*4+3], s3);
    atomicAdd(&csq[cg*4+0], q0); atomicAdd(&csq[cg*4+1], q1);
    atomicAdd(&csq[cg*4+2], q2); atomicAdd(&csq[cg*4+3], q3);
    __syncthreads();
    if (tid < 128) { atomicAdd(&colsum[tid], csum[tid]); atomicAdd(&colsq[tid], csq[tid]); }
}

// ---------------- small GEMM + bias (M multiple of 32, K=N=128) ----------------
__global__ __launch_bounds__(256) void k_gemm_bias(
    const float* __restrict__ xin, const float* __restrict__ W, const float* __restrict__ bias,
    float* __restrict__ out)
{
    __shared__ float xs[32][132];
    __shared__ float wcs[32][128];
    const int tid = threadIdx.x;
    const int row0 = blockIdx.x * 32;
    for (int i = tid; i < 32 * 32; i += 256) {
        int r = i >> 5, c4 = (i & 31) * 4;
        *(float4*)&xs[r][c4] = *(const float4*)&xin[(size_t)(row0 + r) * 128 + c4];
    }
    const int cg = tid & 31, rg = tid >> 5;
    float acc[4][4];
    #pragma unroll
    for (int r = 0; r < 4; ++r)
        #pragma unroll
        for (int c = 0; c < 4; ++c) acc[r][c] = 0.f;
    for (int kc = 0; kc < 4; ++kc) {
        __syncthreads();
        for (int i = tid; i < 32 * 32; i += 256) {
            int k = i >> 5, c4 = (i & 31) * 4;
            *(float4*)&wcs[k][c4] = *(const float4*)&W[(kc * 32 + k) * 128 + c4];
        }
        __syncthreads();
        #pragma unroll
        for (int k4 = 0; k4 < 8; ++k4) {
            float4 xv[4];
            #pragma unroll
            for (int r = 0; r < 4; ++r)
                xv[r] = *(float4*)&xs[rg * 4 + r][kc * 32 + k4 * 4];
            #pragma unroll
            for (int kk = 0; kk < 4; ++kk) {
                float4 w1 = *(float4*)&wcs[k4 * 4 + kk][cg * 4];
                #pragma unroll
                for (int r = 0; r < 4; ++r) {
                    float xk = (&xv[r].x)[kk];
                    acc[r][0] += xk * w1.x;
                    acc[r][1] += xk * w1.y;
                    acc[r][2] += xk * w1.z;
                    acc[r][3] += xk * w1.w;
                }
            }
        }
    }
    const float4 b4 = *(const float4*)&bias[cg * 4];
    #pragma unroll
    for (int r = 0; r < 4; ++r) {
        float4 o;
        o.x = acc[r][0] + b4.x; o.y = acc[r][1] + b4.y;
        o.z = acc[r][2] + b4.z; o.w = acc[r][3] + b4.w;
        *(float4*)&out[(size_t)(row0 + rg * 4 + r) * 128 + cg * 4] = o;
    }
}

// ---------------- BN finalize: scale/shift per column ----------------
__global__ void k_bn_finalize(const float* __restrict__ sum, const float* __restrict__ sq,
                              const float* __restrict__ gamma, const float* __restrict__ beta,
                              float* __restrict__ scale, float* __restrict__ shift, float invM)
{
    int c = threadIdx.x;
    float mu = sum[c] * invM;
    float var = sq[c] * invM - mu * mu;
    float sc = gamma[c] * rsqrtf(var + 1e-5f);
    scale[c] = sc;
    shift[c] = beta[c] - mu * sc;
}

// ---------------- subgraph mean: sub[g*S+s][c] = mean_n x ----------------
__global__ void k_submean(const float* __restrict__ x, float* __restrict__ sub) {
    int gs = blockIdx.x; int c = threadIdx.x;
    size_t base = (size_t)gs * 32 * 128;
    float s = 0.f;
    #pragma unroll
    for (int n = 0; n < 32; ++n) s += x[base + n * 128 + c];
    sub[(size_t)gs * 128 + c] = s * (1.f / 32.f);
}

// ---------------- per-graph MHA: scores -> softmax -> head-mean ----------------
__global__ __launch_bounds__(128) void k_attention(const float* __restrict__ q, const float* __restrict__ kmat,
                                                   float* __restrict__ attn, float* __restrict__ heat)
{
    int g = blockIdx.x, tid = threadIdx.x;
    __shared__ float qs[32][128];
    __shared__ float ks[32][128];
    __shared__ float attn_s[1024];
    for (int i = tid; i < 32 * 32; i += 128) {
        int r = i >> 5, c4 = (i & 31) * 4;
        *(float4*)&qs[r][c4] = *(const float4*)&q[((size_t)g * 32 + r) * 128 + c4];
        *(float4*)&ks[r][c4] = *(const float4*)&kmat[((size_t)g * 32 + r) * 128 + c4];
    }
    for (int i = tid; i < 1024; i += 128) attn_s[i] = 0.f;
    __syncthreads();
    int h = tid >> 5, i = tid & 31;   // thread = one (head, q-row)
    float qreg[32];
    #pragma unroll
    for (int d = 0; d < 32; ++d) qreg[d] = qs[i][h * 32 + d];
    float sc[32];
    const float scale = 0.17677669529663687f; // 1/sqrt(32)
    float mx = -1e30f;
    #pragma unroll
    for (int j = 0; j < 32; ++j) {
        float d = 0.f;
        #pragma unroll
        for (int d0 = 0; d0 < 32; ++d0) d += qreg[d0] * ks[j][h * 32 + d0];
        d *= scale;
        sc[j] = d;
        mx = fmaxf(mx, d);
    }
    float ssum = 0.f;
    #pragma unroll
    for (int j = 0; j < 32; ++j) { float e = __expf(sc[j] - mx); sc[j] = e; ssum += e; }
    float inv = 0.25f / ssum;  // head-mean folded in
    #pragma unroll
    for (int j = 0; j < 32; ++j) atomicAdd(&attn_s[i * 32 + j], sc[j] * inv);
    __syncthreads();
    for (int idx = tid; idx < 1024; idx += 128) {
        float v = attn_s[idx];
        attn[(size_t)g * 1024 + idx] = v;
        if (heat != nullptr && g == 127) heat[idx] = v;
    }
}

// ---------------- x_atten[g,n] = sum_s attn[g,s,n] * x[g,s,n] ----------------
__global__ void k_xatten(const float* __restrict__ x, const float* __restrict__ attn, float* __restrict__ xat) {
    int gn = blockIdx.x; int g = gn >> 5, n = gn & 31;
    int c = threadIdx.x;
    __shared__ float a_s[32];
    if (c < 32) a_s[c] = attn[(size_t)g * 1024 + c * 32 + n];
    __syncthreads();
    float s = 0.f;
    #pragma unroll
    for (int s2 = 0; s2 < 32; ++s2) s += a_s[s2] * x[(((size_t)g * 32 + s2) * 32 + n) * 128 + c];
    xat[(size_t)gn * 128 + c] = s;
}

// ---------------- x = relu(BN1(h1pre) + BN2(h2pre) broadcast) ----------------
__global__ __launch_bounds__(256) void k_update(
    const float* __restrict__ hpre, const float* __restrict__ scA, const float* __restrict__ shA,
    const float* __restrict__ h2pre, const float* __restrict__ scB, const float* __restrict__ shB,
    float* __restrict__ x)
{
    int i = blockIdx.x * 256 + threadIdx.x;   // one float4 each; grid covers T*32
    int t = i >> 5; int c = (i & 31) * 4;
    int g = t >> 10, n = t & 31;
    size_t r2 = ((size_t)(g * 32 + n)) * 128 + c;
    float4 h1 = *(const float4*)&hpre[(size_t)t * 128 + c];
    float4 h2 = *(const float4*)&h2pre[r2];
    float4 sa = *(const float4*)&scA[c]; float4 ha = *(const float4*)&shA[c];
    float4 sb = *(const float4*)&scB[c]; float4 hb = *(const float4*)&shB[c];
    float4 o;
    o.x = fmaxf(h1.x * sa.x + ha.x + h2.x * sb.x + hb.x, 0.f);
    o.y = fmaxf(h1.y * sa.y + ha.y + h2.y * sb.y + hb.y, 0.f);
    o.z = fmaxf(h1.z * sa.z + ha.z + h2.z * sb.z + hb.z, 0.f);
    o.w = fmaxf(h1.w * sa.w + ha.w + h2.w * sb.w + hb.w, 0.f);
    *(float4*)&x[(size_t)t * 128 + c] = o;
}

// ---------------- graph mean-pool ----------------
__global__ void k_pool(const float* __restrict__ x, float* __restrict__ hg) {
    int g = blockIdx.x, part = blockIdx.y, c = threadIdx.x;
    float s = 0.f;
    size_t base = ((size_t)g * 1024 + part * 128) * 128;
    for (int r = 0; r < 128; ++r) s += x[base + (size_t)r * 128 + c];
    atomicAdd(&hg[g * 128 + c], s * (1.f / 1024.f));
}

// ---------------- final MLP head ----------------
__global__ __launch_bounds__(256) void k_dense(const float* __restrict__ hg, const float* __restrict__ Wf1,
    const float* __restrict__ bf1, const float* __restrict__ Wf2, const float* __restrict__ bf2,
    float* __restrict__ out)
{
    int g = blockIdx.x, tid = threadIdx.x;
    __shared__ float hgs[128];
    __shared__ float hid[256];
    if (tid < 128) hgs[tid] = hg[g * 128 + tid];
    __syncthreads();
    float a = bf1[tid];
    for (int k = 0; k < 128; ++k) a += hgs[k] * Wf1[k * 256 + tid];
    hid[tid] = fmaxf(a, 0.f);
    __syncthreads();
    if (tid < 10) {
        float o = bf2[tid];
        for (int k = 0; k < 256; ++k) o += hid[k] * Wf2[k * 10 + tid];
        out[g * 10 + tid] = o;
    }
}

extern "C" void kernel_launch(void* const* d_in, const int* in_sizes, int n_in,
                              void* d_out, int out_size, void* d_ws, size_t ws_size,
                              hipStream_t stream)
{
    (void)in_sizes; (void)n_in; (void)out_size; (void)ws_size;
    const float* x0  = (const float*)d_in[0];
    const int*   ei  = (const int*)d_in[1];
    const int*   oei = (const int*)d_in[2];
    const float* Wr1 = (const float*)d_in[3];
    const float* Wn1 = (const float*)d_in[4];
    const float* b1  = (const float*)d_in[5];
    const float* g1  = (const float*)d_in[6];
    const float* be1 = (const float*)d_in[7];
    const float* Wr2 = (const float*)d_in[8];
    const float* Wn2 = (const float*)d_in[9];
    const float* b2  = (const float*)d_in[10];
    const float* g2  = (const float*)d_in[11];
    const float* be2 = (const float*)d_in[12];
    const float* Wq  = (const float*)d_in[13];
    const float* bq  = (const float*)d_in[14];
    const float* Wk  = (const float*)d_in[15];
    const float* bk  = (const float*)d_in[16];
    const float* Wf1 = (const float*)d_in[17];
    const float* bf1 = (const float*)d_in[18];
    const float* Wf2 = (const float*)d_in[19];
    const float* bf2 = (const float*)d_in[20];
    float* out = (float*)d_out;
    float* x = (float*)x0;   // in-place update; harness restores d_in before every launch

    char* w = (char*)d_ws;
    size_t off = 0;
    auto alloc = [&](size_t bytes) { void* p = w + off; off = (off + bytes + 255) & ~(size_t)255; return p; };
    float* h1pre  = (float*)alloc((size_t)T_ * D_ * 4);
    float* sub    = (float*)alloc((size_t)G_ * S_ * D_ * 4);
    float* qbuf   = (float*)alloc((size_t)G_ * S_ * D_ * 4);
    float* kbuf   = (float*)alloc((size_t)G_ * S_ * D_ * 4);
    float* attnb  = (float*)alloc((size_t)G_ * S_ * S_ * 4);
    float* xat    = (float*)alloc((size_t)TO_ * D_ * 4);
    float* h2pre  = (float*)alloc((size_t)TO_ * D_ * 4);
    float* stats  = (float*)alloc(1024 * 4);   // sumA sqA sumB sqB | scaleA shiftA scaleB shiftB
    float* hgraph = (float*)alloc((size_t)G_ * D_ * 4);
    int* rowptr  = (int*)alloc((T_ + 1) * 4);
    int* deg     = (int*)alloc(T_ * 4);
    int* incl    = (int*)alloc(T_ * 4);
    int* bsum    = (int*)alloc(512 * 4);
    int* bexcl   = (int*)alloc(512 * 4);
    int* cursor  = (int*)alloc(T_ * 4);
    int* colsrc  = (int*)alloc((size_t)E_ * 4);
    int* orowptr = (int*)alloc((TO_ + 1) * 4);
    int* odeg    = (int*)alloc(TO_ * 4);
    int* oincl   = (int*)alloc(TO_ * 4);
    int* obsum   = (int*)alloc(512 * 4);
    int* obexcl  = (int*)alloc(512 * 4);
    int* ocursor = (int*)alloc(TO_ * 4);
    int* ocolsrc = (int*)alloc((size_t)EO_ * 4);

    float* sumA = stats + 0,  *sqA = stats + 128;
    float* sumB = stats + 256, *sqB = stats + 384;
    float* scaleA = stats + 512, *shiftA = stats + 640;
    float* scaleB = stats + 768, *shiftB = stats + 896;

    hipMemsetAsync(deg, 0, (size_t)T_ * 4, stream);
    hipMemsetAsync(odeg, 0, (size_t)TO_ * 4, stream);
    hipMemsetAsync(hgraph, 0, (size_t)G_ * D_ * 4, stream);

    // CSR for batched subgraph edges (reused across all 3 layers)
    k_hist<<<E_ / 256, 256, 0, stream>>>(ei + E_, deg, E_);
    k_scan1<<<T_ / 256, 256, 0, stream>>>(deg, incl, bsum, T_);
    k_scan2<<<1, 512, 0, stream>>>(bsum, bexcl, T_ / 256);
    k_scan3<<<T_ / 256, 256, 0, stream>>>(incl, bexcl, rowptr, T_);
    k_copyint<<<T_ / 256, 256, 0, stream>>>(rowptr, cursor, T_);
    k_fill<<<E_ / 256, 256, 0, stream>>>(ei, ei + E_, cursor, colsrc, E_);
    // CSR for original-graph edges
    k_hist<<<EO_ / 256, 256, 0, stream>>>(oei + EO_, odeg, EO_);
    k_scan1<<<TO_ / 256, 256, 0, stream>>>(odeg, oincl, obsum, TO_);
    k_scan2<<<1, 512, 0, stream>>>(obsum, obexcl, TO_ / 256);
    k_scan3<<<TO_ / 256, 256, 0, stream>>>(oincl, obexcl, orowptr, TO_);
    k_copyint<<<TO_ / 256, 256, 0, stream>>>(orowptr, ocursor, TO_);
    k_fill<<<EO_ / 256, 256, 0, stream>>>(oei, oei + EO_, ocursor, ocolsrc, EO_);

    for (int i = 0; i < 3; ++i) {
        hipMemsetAsync(stats, 0, 512 * 4, stream);
        k_conv<<<T_ / 32, 256, 0, stream>>>(x, rowptr, colsrc,
            Wr1 + (size_t)i * D_ * D_, Wn1 + (size_t)i * D_ * D_, b1 + i * D_, h1pre, sumA, sqA);
        k_bn_finalize<<<1, 128, 0, stream>>>(sumA, sqA, g1 + i * D_, be1 + i * D_, scaleA, shiftA, 1.0f / T_);
        k_submean<<<G_ * S_, 128, 0, stream>>>(x, sub);
        k_gemm_bias<<<(G_ * S_) / 32, 256, 0, stream>>>(sub, Wq + (size_t)i * D_ * D_, bq + i * D_, qbuf);
        k_gemm_bias<<<(G_ * S_) / 32, 256, 0, stream>>>(sub, Wk + (size_t)i * D_ * D_, bk + i * D_, kbuf);
        k_attention<<<G_, 128, 0, stream>>>(qbuf, kbuf, attnb, (i == 2) ? (out + G_ * NTASK_) : nullptr);
        k_xatten<<<G_ * N_, 128, 0, stream>>>(x, attnb, xat);
        k_conv<<<TO_ / 32, 256, 0, stream>>>(xat, orowptr, ocolsrc,
            Wr2 + (size_t)i * D_ * D_, Wn2 + (size_t)i * D_ * D_, b2 + i * D_, h2pre, sumB, sqB);
        k_bn_finalize<<<1, 128, 0, stream>>>(sumB, sqB, g2 + i * D_, be2 + i * D_, scaleB, shiftB, 1.0f / TO_);
        k_update<<<(T_ * 32) / 256, 256, 0, stream>>>(h1pre, scaleA, shiftA, h2pre, scaleB, shiftB, x);
    }
    k_pool<<<dim3(G_, 8), 128, 0, stream>>>(x, hgraph);
    k_dense<<<G_, 256, 0, stream>>>(hgraph, Wf1, bf1, Wf2, bf2, out);
}

// Round 2
// 1335.151 us; speedup vs baseline: 1.9726x; 1.9726x over previous
//
#include <hip/hip_runtime.h>

#define G_   128
#define S_   32
#define N_   32
#define D_   128
#define T_   (G_*S_*N_)    // 131072
#define TO_  (G_*N_)       // 4096
#define E_   1048576
#define EO_  16384
#define HD_  32
#define NTASK_ 10

// ---------------- CSR build ----------------
__global__ void k_hist(const int* __restrict__ dst, int* __restrict__ deg, int n) {
    int e = blockIdx.x * 256 + threadIdx.x;
    if (e < n) atomicAdd(&deg[dst[e]], 1);
}

__global__ void k_scan1(const int* __restrict__ deg, int* __restrict__ incl, int* __restrict__ bsum, int n) {
    __shared__ int tmp[256];
    int i = blockIdx.x * 256 + threadIdx.x;
    int v = (i < n) ? deg[i] : 0;
    tmp[threadIdx.x] = v;
    __syncthreads();
    for (int off = 1; off < 256; off <<= 1) {
        int t = (threadIdx.x >= off) ? tmp[threadIdx.x - off] : 0;
        __syncthreads();
        tmp[threadIdx.x] += t;
        __syncthreads();
    }
    if (i < n) incl[i] = tmp[threadIdx.x];
    if (threadIdx.x == 255) bsum[blockIdx.x] = tmp[255];
}

__global__ void k_scan2(const int* __restrict__ bsum, int* __restrict__ bexcl, int nb) {
    __shared__ int tmp[512];
    int t = threadIdx.x;
    int v = (t < nb) ? bsum[t] : 0;
    tmp[t] = v;
    __syncthreads();
    for (int off = 1; off < 512; off <<= 1) {
        int u = (t >= off) ? tmp[t - off] : 0;
        __syncthreads();
        tmp[t] += u;
        __syncthreads();
    }
    if (t < nb) bexcl[t] = tmp[t] - v;
}

__global__ void k_scan3(const int* __restrict__ incl, const int* __restrict__ bexcl, int* __restrict__ rowptr, int n) {
    int i = blockIdx.x * 256 + threadIdx.x;
    if (i < n) rowptr[i + 1] = incl[i] + bexcl[blockIdx.x];
    if (i == 0) rowptr[0] = 0;
}

__global__ void k_copyint(const int* __restrict__ a, int* __restrict__ b, int n) {
    int i = blockIdx.x * 256 + threadIdx.x;
    if (i < n) b[i] = a[i];
}

__global__ void k_fill(const int* __restrict__ src, const int* __restrict__ dst,
                       int* __restrict__ cursor, int* __restrict__ colsrc, int n) {
    int e = blockIdx.x * 256 + threadIdx.x;
    if (e < n) {
        int pos = atomicAdd(&cursor[dst[e]], 1);
        colsrc[pos] = src[e];
    }
}

// ---------------- CSR neighbor-sum aggregation (high occupancy, ILP-4) ----------------
// 8 nodes per 256-thread block; 32 lanes per node (float4 each); no LDS.
__global__ __launch_bounds__(256) void k_agg(
    const float* __restrict__ x, const int* __restrict__ rowptr, const int* __restrict__ colsrc,
    float* __restrict__ agg, int n)
{
    int nid = blockIdx.x * 8 + (threadIdx.x >> 5);
    int lane = threadIdx.x & 31;
    if (nid >= n) return;
    int e0 = rowptr[nid], e1 = rowptr[nid + 1];
    float4 acc = make_float4(0.f, 0.f, 0.f, 0.f);
    int e = e0;
    for (; e + 4 <= e1; e += 4) {
        int s0 = colsrc[e + 0], s1 = colsrc[e + 1], s2 = colsrc[e + 2], s3 = colsrc[e + 3];
        float4 v0 = *(const float4*)&x[(size_t)s0 * 128 + lane * 4];
        float4 v1 = *(const float4*)&x[(size_t)s1 * 128 + lane * 4];
        float4 v2 = *(const float4*)&x[(size_t)s2 * 128 + lane * 4];
        float4 v3 = *(const float4*)&x[(size_t)s3 * 128 + lane * 4];
        acc.x += (v0.x + v1.x) + (v2.x + v3.x);
        acc.y += (v0.y + v1.y) + (v2.y + v3.y);
        acc.z += (v0.z + v1.z) + (v2.z + v3.z);
        acc.w += (v0.w + v1.w) + (v2.w + v3.w);
    }
    for (; e < e1; ++e) {
        int s = colsrc[e];
        float4 v = *(const float4*)&x[(size_t)s * 128 + lane * 4];
        acc.x += v.x; acc.y += v.y; acc.z += v.z; acc.w += v.w;
    }
    *(float4*)&agg[(size_t)nid * 128 + lane * 4] = acc;
}

// ---------------- dense GraphConv GEMM + BN-stats ----------------
// hpre = xin @ Wr + agg @ Wn + bias; per-column sum/sumsq via atomics.
// 64 rows x 128 cols per 256-thread block; 8x4 register tile per thread.
// NOTE: hpre may alias agg (block reads only its own rows, writes after reads).
__global__ __launch_bounds__(256) void k_conv2(
    const float* __restrict__ xin, const float* __restrict__ agg,
    const float* __restrict__ Wr, const float* __restrict__ Wn, const float* __restrict__ bias,
    float* __restrict__ hpre, float* __restrict__ colsum, float* __restrict__ colsq)
{
    __shared__ float xs[64][36];
    __shared__ float wls[32][128];
    __shared__ float csum[128];
    __shared__ float csq[128];
    const int tid = threadIdx.x;
    const int row0 = blockIdx.x * 64;
    const int cg = tid & 31;   // cols cg*4 .. cg*4+3
    const int rg = tid >> 5;   // rows rg*8 .. rg*8+7
    if (tid < 128) { csum[tid] = 0.f; csq[tid] = 0.f; }
    float acc[8][4];
    #pragma unroll
    for (int r = 0; r < 8; ++r)
        #pragma unroll
        for (int c = 0; c < 4; ++c) acc[r][c] = 0.f;

    for (int phase = 0; phase < 2; ++phase) {
        const float* A = phase ? agg : xin;
        const float* W = phase ? Wn : Wr;
        for (int kc = 0; kc < 4; ++kc) {
            __syncthreads();
            for (int i = tid; i < 512; i += 256) {      // 64 rows x 32 k
                int r = i >> 3, c4 = (i & 7) * 4;
                *(float4*)&xs[r][c4] = *(const float4*)&A[(size_t)(row0 + r) * 128 + kc * 32 + c4];
            }
            for (int i = tid; i < 1024; i += 256) {     // 32 k x 128 n
                int k = i >> 5, c4 = (i & 31) * 4;
                *(float4*)&wls[k][c4] = *(const float4*)&W[(size_t)(kc * 32 + k) * 128 + c4];
            }
            __syncthreads();
            #pragma unroll
            for (int k4 = 0; k4 < 8; ++k4) {
                float4 xv[8];
                #pragma unroll
                for (int r = 0; r < 8; ++r) xv[r] = *(float4*)&xs[rg * 8 + r][k4 * 4];
                #pragma unroll
                for (int kk = 0; kk < 4; ++kk) {
                    float4 w = *(float4*)&wls[k4 * 4 + kk][cg * 4];
                    #pragma unroll
                    for (int r = 0; r < 8; ++r) {
                        float a = (&xv[r].x)[kk];
                        acc[r][0] += a * w.x;
                        acc[r][1] += a * w.y;
                        acc[r][2] += a * w.z;
                        acc[r][3] += a * w.w;
                    }
                }
            }
        }
    }
    const float4 b4 = *(const float4*)&bias[cg * 4];
    float s0=0,s1=0,s2=0,s3=0,q0=0,q1=0,q2=0,q3=0;
    #pragma unroll
    for (int r = 0; r < 8; ++r) {
        float4 o;
        o.x = acc[r][0] + b4.x; o.y = acc[r][1] + b4.y;
        o.z = acc[r][2] + b4.z; o.w = acc[r][3] + b4.w;
        *(float4*)&hpre[(size_t)(row0 + rg * 8 + r) * 128 + cg * 4] = o;
        s0 += o.x; s1 += o.y; s2 += o.z; s3 += o.w;
        q0 += o.x*o.x; q1 += o.y*o.y; q2 += o.z*o.z; q3 += o.w*o.w;
    }
    atomicAdd(&csum[cg*4+0], s0); atomicAdd(&csum[cg*4+1], s1);
    atomicAdd(&csum[cg*4+2], s2); atomicAdd(&csum[cg*4+3], s3);
    atomicAdd(&csq[cg*4+0], q0); atomicAdd(&csq[cg*4+1], q1);
    atomicAdd(&csq[cg*4+2], q2); atomicAdd(&csq[cg*4+3], q3);
    __syncthreads();
    if (tid < 128) { atomicAdd(&colsum[tid], csum[tid]); atomicAdd(&colsq[tid], csq[tid]); }
}

// ---------------- small GEMM + bias (M multiple of 32, K=N=128) ----------------
__global__ __launch_bounds__(256) void k_gemm_bias(
    const float* __restrict__ xin, const float* __restrict__ W, const float* __restrict__ bias,
    float* __restrict__ out)
{
    __shared__ float xs[32][132];
    __shared__ float wcs[32][128];
    const int tid = threadIdx.x;
    const int row0 = blockIdx.x * 32;
    for (int i = tid; i < 32 * 32; i += 256) {
        int r = i >> 5, c4 = (i & 31) * 4;
        *(float4*)&xs[r][c4] = *(const float4*)&xin[(size_t)(row0 + r) * 128 + c4];
    }
    const int cg = tid & 31, rg = tid >> 5;
    float acc[4][4];
    #pragma unroll
    for (int r = 0; r < 4; ++r)
        #pragma unroll
        for (int c = 0; c < 4; ++c) acc[r][c] = 0.f;
    for (int kc = 0; kc < 4; ++kc) {
        __syncthreads();
        for (int i = tid; i < 32 * 32; i += 256) {
            int k = i >> 5, c4 = (i & 31) * 4;
            *(float4*)&wcs[k][c4] = *(const float4*)&W[(kc * 32 + k) * 128 + c4];
        }
        __syncthreads();
        #pragma unroll
        for (int k4 = 0; k4 < 8; ++k4) {
            float4 xv[4];
            #pragma unroll
            for (int r = 0; r < 4; ++r)
                xv[r] = *(float4*)&xs[rg * 4 + r][kc * 32 + k4 * 4];
            #pragma unroll
            for (int kk = 0; kk < 4; ++kk) {
                float4 w1 = *(float4*)&wcs[k4 * 4 + kk][cg * 4];
                #pragma unroll
                for (int r = 0; r < 4; ++r) {
                    float xk = (&xv[r].x)[kk];
                    acc[r][0] += xk * w1.x;
                    acc[r][1] += xk * w1.y;
                    acc[r][2] += xk * w1.z;
                    acc[r][3] += xk * w1.w;
                }
            }
        }
    }
    const float4 b4 = *(const float4*)&bias[cg * 4];
    #pragma unroll
    for (int r = 0; r < 4; ++r) {
        float4 o;
        o.x = acc[r][0] + b4.x; o.y = acc[r][1] + b4.y;
        o.z = acc[r][2] + b4.z; o.w = acc[r][3] + b4.w;
        *(float4*)&out[(size_t)(row0 + rg * 4 + r) * 128 + cg * 4] = o;
    }
}

// ---------------- BN finalize: scale/shift per column ----------------
__global__ void k_bn_finalize(const float* __restrict__ sum, const float* __restrict__ sq,
                              const float* __restrict__ gamma, const float* __restrict__ beta,
                              float* __restrict__ scale, float* __restrict__ shift, float invM)
{
    int c = threadIdx.x;
    float mu = sum[c] * invM;
    float var = sq[c] * invM - mu * mu;
    float sc = gamma[c] * rsqrtf(var + 1e-5f);
    scale[c] = sc;
    shift[c] = beta[c] - mu * sc;
}

// ---------------- initial subgraph mean (layer 1 only) ----------------
__global__ void k_submean(const float* __restrict__ x, float* __restrict__ sub) {
    int gs = blockIdx.x; int c = threadIdx.x;
    size_t base = (size_t)gs * 32 * 128;
    float s = 0.f;
    #pragma unroll
    for (int n = 0; n < 32; ++n) s += x[base + n * 128 + c];
    sub[(size_t)gs * 128 + c] = s * (1.f / 32.f);
}

// ---------------- per-graph MHA: scores -> softmax -> head-mean ----------------
__global__ __launch_bounds__(128) void k_attention(const float* __restrict__ q, const float* __restrict__ kmat,
                                                   float* __restrict__ attn, float* __restrict__ heat)
{
    int g = blockIdx.x, tid = threadIdx.x;
    __shared__ float qs[32][128];
    __shared__ float ks[32][128];
    __shared__ float attn_s[1024];
    for (int i = tid; i < 32 * 32; i += 128) {
        int r = i >> 5, c4 = (i & 31) * 4;
        *(float4*)&qs[r][c4] = *(const float4*)&q[((size_t)g * 32 + r) * 128 + c4];
        *(float4*)&ks[r][c4] = *(const float4*)&kmat[((size_t)g * 32 + r) * 128 + c4];
    }
    for (int i = tid; i < 1024; i += 128) attn_s[i] = 0.f;
    __syncthreads();
    int h = tid >> 5, i = tid & 31;   // thread = one (head, q-row)
    float qreg[32];
    #pragma unroll
    for (int d = 0; d < 32; ++d) qreg[d] = qs[i][h * 32 + d];
    float sc[32];
    const float scale = 0.17677669529663687f; // 1/sqrt(32)
    float mx = -1e30f;
    #pragma unroll
    for (int j = 0; j < 32; ++j) {
        float d = 0.f;
        #pragma unroll
        for (int d0 = 0; d0 < 32; ++d0) d += qreg[d0] * ks[j][h * 32 + d0];
        d *= scale;
        sc[j] = d;
        mx = fmaxf(mx, d);
    }
    float ssum = 0.f;
    #pragma unroll
    for (int j = 0; j < 32; ++j) { float e = __expf(sc[j] - mx); sc[j] = e; ssum += e; }
    float inv = 0.25f / ssum;  // head-mean folded in
    #pragma unroll
    for (int j = 0; j < 32; ++j) atomicAdd(&attn_s[i * 32 + j], sc[j] * inv);
    __syncthreads();
    for (int idx = tid; idx < 1024; idx += 128) {
        float v = attn_s[idx];
        attn[(size_t)g * 1024 + idx] = v;
        if (heat != nullptr && g == 127) heat[idx] = v;
    }
}

// ---------------- x_atten[g,n] = sum_s attn[g,s,n] * x[g,s,n] ----------------
__global__ void k_xatten(const float* __restrict__ x, const float* __restrict__ attn, float* __restrict__ xat) {
    int gn = blockIdx.x; int g = gn >> 5, n = gn & 31;
    int c = threadIdx.x;
    __shared__ float a_s[32];
    if (c < 32) a_s[c] = attn[(size_t)g * 1024 + c * 32 + n];
    __syncthreads();
    float s = 0.f;
    #pragma unroll
    for (int s2 = 0; s2 < 32; ++s2) s += a_s[s2] * x[(((size_t)g * 32 + s2) * 32 + n) * 128 + c];
    xat[(size_t)gn * 128 + c] = s;
}

// ---------------- x = relu(BN1(h1pre) + BN2(h2pre) bcast); fused next-layer submean ----------------
__global__ __launch_bounds__(256) void k_update(
    const float* __restrict__ hpre, const float* __restrict__ scA, const float* __restrict__ shA,
    const float* __restrict__ h2pre, const float* __restrict__ scB, const float* __restrict__ shB,
    float* __restrict__ x, float* __restrict__ sub)
{
    int gs = blockIdx.x;           // g*32 + s
    int g = gs >> 5;
    int tid = threadIdx.x;
    int cg = tid & 31, ng = tid >> 5;   // 8 node-groups
    __shared__ float red[8][132];
    const int c4 = cg * 4;
    float4 sa = *(const float4*)&scA[c4]; float4 ha = *(const float4*)&shA[c4];
    float4 sb = *(const float4*)&scB[c4]; float4 hb = *(const float4*)&shB[c4];
    float4 ssum = make_float4(0.f, 0.f, 0.f, 0.f);
    for (int n = ng; n < 32; n += 8) {
        size_t t = (size_t)gs * 32 + n;
        float4 h1 = *(const float4*)&hpre[t * 128 + c4];
        float4 h2 = *(const float4*)&h2pre[((size_t)g * 32 + n) * 128 + c4];
        float4 o;
        o.x = fmaxf(h1.x * sa.x + ha.x + h2.x * sb.x + hb.x, 0.f);
        o.y = fmaxf(h1.y * sa.y + ha.y + h2.y * sb.y + hb.y, 0.f);
        o.z = fmaxf(h1.z * sa.z + ha.z + h2.z * sb.z + hb.z, 0.f);
        o.w = fmaxf(h1.w * sa.w + ha.w + h2.w * sb.w + hb.w, 0.f);
        *(float4*)&x[t * 128 + c4] = o;
        ssum.x += o.x; ssum.y += o.y; ssum.z += o.z; ssum.w += o.w;
    }
    *(float4*)&red[ng][c4] = ssum;
    __syncthreads();
    if (ng == 0) {
        float4 s = make_float4(0.f, 0.f, 0.f, 0.f);
        #pragma unroll
        for (int r = 0; r < 8; ++r) {
            float4 v = *(float4*)&red[r][c4];
            s.x += v.x; s.y += v.y; s.z += v.z; s.w += v.w;
        }
        const float inv = 1.f / 32.f;
        s.x *= inv; s.y *= inv; s.z *= inv; s.w *= inv;
        *(float4*)&sub[(size_t)gs * 128 + c4] = s;
    }
}

// ---------------- final head: graph mean over sub + 2-layer MLP ----------------
__global__ __launch_bounds__(256) void k_dense(const float* __restrict__ sub, const float* __restrict__ Wf1,
    const float* __restrict__ bf1, const float* __restrict__ Wf2, const float* __restrict__ bf2,
    float* __restrict__ out)
{
    int g = blockIdx.x, tid = threadIdx.x;
    __shared__ float hgs[128];
    __shared__ float hid[256];
    if (tid < 128) {
        float s = 0.f;
        for (int ss = 0; ss < 32; ++ss) s += sub[((size_t)g * 32 + ss) * 128 + tid];
        hgs[tid] = s * (1.f / 32.f);
    }
    __syncthreads();
    float a = bf1[tid];
    for (int k = 0; k < 128; ++k) a += hgs[k] * Wf1[k * 256 + tid];
    hid[tid] = fmaxf(a, 0.f);
    __syncthreads();
    if (tid < 10) {
        float o = bf2[tid];
        for (int k = 0; k < 256; ++k) o += hid[k] * Wf2[k * 10 + tid];
        out[g * 10 + tid] = o;
    }
}

extern "C" void kernel_launch(void* const* d_in, const int* in_sizes, int n_in,
                              void* d_out, int out_size, void* d_ws, size_t ws_size,
                              hipStream_t stream)
{
    (void)in_sizes; (void)n_in; (void)out_size; (void)ws_size;
    const float* x0  = (const float*)d_in[0];
    const int*   ei  = (const int*)d_in[1];
    const int*   oei = (const int*)d_in[2];
    const float* Wr1 = (const float*)d_in[3];
    const float* Wn1 = (const float*)d_in[4];
    const float* b1  = (const float*)d_in[5];
    const float* g1  = (const float*)d_in[6];
    const float* be1 = (const float*)d_in[7];
    const float* Wr2 = (const float*)d_in[8];
    const float* Wn2 = (const float*)d_in[9];
    const float* b2  = (const float*)d_in[10];
    const float* g2  = (const float*)d_in[11];
    const float* be2 = (const float*)d_in[12];
    const float* Wq  = (const float*)d_in[13];
    const float* bq  = (const float*)d_in[14];
    const float* Wk  = (const float*)d_in[15];
    const float* bk  = (const float*)d_in[16];
    const float* Wf1 = (const float*)d_in[17];
    const float* bf1 = (const float*)d_in[18];
    const float* Wf2 = (const float*)d_in[19];
    const float* bf2 = (const float*)d_in[20];
    float* out = (float*)d_out;
    float* x = (float*)x0;   // in-place update; harness restores d_in before every launch

    char* w = (char*)d_ws;
    size_t off = 0;
    auto alloc = [&](size_t bytes) { void* p = w + off; off = (off + bytes + 255) & ~(size_t)255; return p; };
    float* agg    = (float*)alloc((size_t)T_ * D_ * 4);   // also aliased as h1pre (safe: block-local RAW)
    float* agg2   = (float*)alloc((size_t)TO_ * D_ * 4);
    float* sub    = (float*)alloc((size_t)G_ * S_ * D_ * 4);
    float* qbuf   = (float*)alloc((size_t)G_ * S_ * D_ * 4);
    float* kbuf   = (float*)alloc((size_t)G_ * S_ * D_ * 4);
    float* attnb  = (float*)alloc((size_t)G_ * S_ * S_ * 4);
    float* xat    = (float*)alloc((size_t)TO_ * D_ * 4);
    float* h2pre  = (float*)alloc((size_t)TO_ * D_ * 4);
    float* stats  = (float*)alloc(1024 * 4);   // sumA sqA sumB sqB | scaleA shiftA scaleB shiftB
    int* rowptr  = (int*)alloc((T_ + 1) * 4);
    int* deg     = (int*)alloc(T_ * 4);
    int* incl    = (int*)alloc(T_ * 4);
    int* bsum    = (int*)alloc(512 * 4);
    int* bexcl   = (int*)alloc(512 * 4);
    int* cursor  = (int*)alloc(T_ * 4);
    int* colsrc  = (int*)alloc((size_t)E_ * 4);
    int* orowptr = (int*)alloc((TO_ + 1) * 4);
    int* odeg    = (int*)alloc(TO_ * 4);
    int* oincl   = (int*)alloc(TO_ * 4);
    int* obsum   = (int*)alloc(512 * 4);
    int* obexcl  = (int*)alloc(512 * 4);
    int* ocursor = (int*)alloc(TO_ * 4);
    int* ocolsrc = (int*)alloc((size_t)EO_ * 4);

    float* h1pre = agg;   // alias
    float* sumA = stats + 0,  *sqA = stats + 128;
    float* sumB = stats + 256, *sqB = stats + 384;
    float* scaleA = stats + 512, *shiftA = stats + 640;
    float* scaleB = stats + 768, *shiftB = stats + 896;

    hipMemsetAsync(deg, 0, (size_t)T_ * 4, stream);
    hipMemsetAsync(odeg, 0, (size_t)TO_ * 4, stream);

    // CSR for batched subgraph edges (reused across all 3 layers)
    k_hist<<<E_ / 256, 256, 0, stream>>>(ei + E_, deg, E_);
    k_scan1<<<T_ / 256, 256, 0, stream>>>(deg, incl, bsum, T_);
    k_scan2<<<1, 512, 0, stream>>>(bsum, bexcl, T_ / 256);
    k_scan3<<<T_ / 256, 256, 0, stream>>>(incl, bexcl, rowptr, T_);
    k_copyint<<<T_ / 256, 256, 0, stream>>>(rowptr, cursor, T_);
    k_fill<<<E_ / 256, 256, 0, stream>>>(ei, ei + E_, cursor, colsrc, E_);
    // CSR for original-graph edges
    k_hist<<<EO_ / 256, 256, 0, stream>>>(oei + EO_, odeg, EO_);
    k_scan1<<<TO_ / 256, 256, 0, stream>>>(odeg, oincl, obsum, TO_);
    k_scan2<<<1, 512, 0, stream>>>(obsum, obexcl, TO_ / 256);
    k_scan3<<<TO_ / 256, 256, 0, stream>>>(oincl, obexcl, orowptr, TO_);
    k_copyint<<<TO_ / 256, 256, 0, stream>>>(orowptr, ocursor, TO_);
    k_fill<<<EO_ / 256, 256, 0, stream>>>(oei, oei + EO_, ocursor, ocolsrc, EO_);

    // initial sub (layer 1); later layers get sub fused from k_update
    k_submean<<<G_ * S_, 128, 0, stream>>>(x, sub);

    for (int i = 0; i < 3; ++i) {
        hipMemsetAsync(stats, 0, 512 * 4, stream);
        // subgraph branch: aggregate then dense conv GEMM (+BN stats)
        k_agg<<<T_ / 8, 256, 0, stream>>>(x, rowptr, colsrc, agg, T_);
        k_conv2<<<T_ / 64, 256, 0, stream>>>(x, agg,
            Wr1 + (size_t)i * D_ * D_, Wn1 + (size_t)i * D_ * D_, b1 + i * D_, h1pre, sumA, sqA);
        k_bn_finalize<<<1, 128, 0, stream>>>(sumA, sqA, g1 + i * D_, be1 + i * D_, scaleA, shiftA, 1.0f / T_);
        // attention branch
        k_gemm_bias<<<(G_ * S_) / 32, 256, 0, stream>>>(sub, Wq + (size_t)i * D_ * D_, bq + i * D_, qbuf);
        k_gemm_bias<<<(G_ * S_) / 32, 256, 0, stream>>>(sub, Wk + (size_t)i * D_ * D_, bk + i * D_, kbuf);
        k_attention<<<G_, 128, 0, stream>>>(qbuf, kbuf, attnb, (i == 2) ? (out + G_ * NTASK_) : nullptr);
        k_xatten<<<G_ * N_, 128, 0, stream>>>(x, attnb, xat);
        // original-graph branch
        k_agg<<<TO_ / 8, 256, 0, stream>>>(xat, orowptr, ocolsrc, agg2, TO_);
        k_conv2<<<TO_ / 64, 256, 0, stream>>>(xat, agg2,
            Wr2 + (size_t)i * D_ * D_, Wn2 + (size_t)i * D_ * D_, b2 + i * D_, h2pre, sumB, sqB);
        k_bn_finalize<<<1, 128, 0, stream>>>(sumB, sqB, g2 + i * D_, be2 + i * D_, scaleB, shiftB, 1.0f / TO_);
        // combine + relu + next-layer submean
        k_update<<<G_ * S_, 256, 0, stream>>>(h1pre, scaleA, shiftA, h2pre, scaleB, shiftB, x, sub);
    }
    k_dense<<<G_, 256, 0, stream>>>(sub, Wf1, bf1, Wf2, bf2, out);
}

// Round 3
// 819.418 us; speedup vs baseline: 3.2142x; 1.6294x over previous
//
#include <hip/hip_runtime.h>

#define G_   128
#define S_   32
#define N_   32
#define D_   128
#define T_   (G_*S_*N_)    // 131072
#define TO_  (G_*N_)       // 4096
#define E_   1048576
#define EO_  16384
#define HD_  32
#define NTASK_ 10

typedef _Float16 h16;
typedef _Float16 half8 __attribute__((ext_vector_type(8)));
typedef _Float16 half4 __attribute__((ext_vector_type(4)));
typedef float f32x16 __attribute__((ext_vector_type(16)));

// ---------------- CSR build ----------------
__global__ void k_hist(const int* __restrict__ dst, int* __restrict__ deg, int n) {
    int e = blockIdx.x * 256 + threadIdx.x;
    if (e < n) atomicAdd(&deg[dst[e]], 1);
}

__global__ void k_scan1(const int* __restrict__ deg, int* __restrict__ incl, int* __restrict__ bsum, int n) {
    __shared__ int tmp[256];
    int i = blockIdx.x * 256 + threadIdx.x;
    int v = (i < n) ? deg[i] : 0;
    tmp[threadIdx.x] = v;
    __syncthreads();
    for (int off = 1; off < 256; off <<= 1) {
        int t = (threadIdx.x >= off) ? tmp[threadIdx.x - off] : 0;
        __syncthreads();
        tmp[threadIdx.x] += t;
        __syncthreads();
    }
    if (i < n) incl[i] = tmp[threadIdx.x];
    if (threadIdx.x == 255) bsum[blockIdx.x] = tmp[255];
}

__global__ void k_scan2(const int* __restrict__ bsum, int* __restrict__ bexcl, int nb) {
    __shared__ int tmp[512];
    int t = threadIdx.x;
    int v = (t < nb) ? bsum[t] : 0;
    tmp[t] = v;
    __syncthreads();
    for (int off = 1; off < 512; off <<= 1) {
        int u = (t >= off) ? tmp[t - off] : 0;
        __syncthreads();
        tmp[t] += u;
        __syncthreads();
    }
    if (t < nb) bexcl[t] = tmp[t] - v;
}

__global__ void k_scan3(const int* __restrict__ incl, const int* __restrict__ bexcl, int* __restrict__ rowptr, int n) {
    int i = blockIdx.x * 256 + threadIdx.x;
    if (i < n) rowptr[i + 1] = incl[i] + bexcl[blockIdx.x];
    if (i == 0) rowptr[0] = 0;
}

__global__ void k_copyint(const int* __restrict__ a, int* __restrict__ b, int n) {
    int i = blockIdx.x * 256 + threadIdx.x;
    if (i < n) b[i] = a[i];
}

__global__ void k_fill(const int* __restrict__ src, const int* __restrict__ dst,
                       int* __restrict__ cursor, int* __restrict__ colsrc, int n) {
    int e = blockIdx.x * 256 + threadIdx.x;
    if (e < n) {
        int pos = atomicAdd(&cursor[dst[e]], 1);
        colsrc[pos] = src[e];
    }
}

// ---------------- weight prep: W[k][n] fp32 -> transposed split fp16 wt[2][n][k] ----------------
// grid (12, 16) x 256: mat = arr*3 + layer, arr in {Wr1,Wn1,Wr2,Wn2}
__global__ void k_prepw(const float* __restrict__ Wr1, const float* __restrict__ Wn1,
                        const float* __restrict__ Wr2, const float* __restrict__ Wn2,
                        h16* __restrict__ wt)
{
    int mat = blockIdx.x;
    int arr = mat / 3, layer = mat % 3;
    const float* W = (arr == 0 ? Wr1 : arr == 1 ? Wn1 : arr == 2 ? Wr2 : Wn2) + (size_t)layer * 16384;
    h16* outh = wt + (size_t)mat * 2 * 16384;
    h16* outl = outh + 16384;
    int base = blockIdx.y * 1024;
    for (int i = threadIdx.x; i < 1024; i += 256) {
        int idx = base + i;
        int k = idx >> 7, n = idx & 127;
        float v = W[idx];
        h16 hi = (h16)v;
        h16 lo = (h16)(v - (float)hi);
        outh[n * 128 + k] = hi;
        outl[n * 128 + k] = lo;
    }
}

// ---------------- x0 fp32 -> xh fp16, fused initial subgraph mean ----------------
__global__ __launch_bounds__(256) void k_tohalf_sub(const float* __restrict__ x0,
        h16* __restrict__ xh, float* __restrict__ sub)
{
    int gs = blockIdx.x, tid = threadIdx.x;
    int cg = tid & 31, rg = tid >> 5;
    int c4 = cg * 4;
    __shared__ float red[8][132];
    float4 ssum = make_float4(0.f, 0.f, 0.f, 0.f);
    for (int n = rg; n < 32; n += 8) {
        size_t t = (size_t)gs * 32 + n;
        float4 v = *(const float4*)&x0[t * 128 + c4];
        half4 o; o[0] = (h16)v.x; o[1] = (h16)v.y; o[2] = (h16)v.z; o[3] = (h16)v.w;
        *(half4*)&xh[t * 128 + c4] = o;
        ssum.x += v.x; ssum.y += v.y; ssum.z += v.z; ssum.w += v.w;
    }
    *(float4*)&red[rg][c4] = ssum;
    __syncthreads();
    if (rg == 0) {
        float4 s = make_float4(0.f, 0.f, 0.f, 0.f);
        #pragma unroll
        for (int r = 0; r < 8; ++r) {
            float4 v = *(float4*)&red[r][c4];
            s.x += v.x; s.y += v.y; s.z += v.z; s.w += v.w;
        }
        const float inv = 1.f / 32.f;
        s.x *= inv; s.y *= inv; s.z *= inv; s.w *= inv;
        *(float4*)&sub[(size_t)gs * 128 + c4] = s;
    }
}

// ---------------- CSR neighbor-sum aggregation (fp16 in/out, fp32 accum) ----------------
__global__ __launch_bounds__(256) void k_agg(
    const h16* __restrict__ x, const int* __restrict__ rowptr, const int* __restrict__ colsrc,
    h16* __restrict__ agg, int n)
{
    int nid = blockIdx.x * 8 + (threadIdx.x >> 5);
    int lane = threadIdx.x & 31;
    if (nid >= n) return;
    int e0 = rowptr[nid], e1 = rowptr[nid + 1];
    float ax = 0.f, ay = 0.f, az = 0.f, aw = 0.f;
    int e = e0;
    for (; e + 4 <= e1; e += 4) {
        int s0 = colsrc[e + 0], s1 = colsrc[e + 1], s2 = colsrc[e + 2], s3 = colsrc[e + 3];
        half4 v0 = *(const half4*)&x[(size_t)s0 * 128 + lane * 4];
        half4 v1 = *(const half4*)&x[(size_t)s1 * 128 + lane * 4];
        half4 v2 = *(const half4*)&x[(size_t)s2 * 128 + lane * 4];
        half4 v3 = *(const half4*)&x[(size_t)s3 * 128 + lane * 4];
        ax += ((float)v0[0] + (float)v1[0]) + ((float)v2[0] + (float)v3[0]);
        ay += ((float)v0[1] + (float)v1[1]) + ((float)v2[1] + (float)v3[1]);
        az += ((float)v0[2] + (float)v1[2]) + ((float)v2[2] + (float)v3[2]);
        aw += ((float)v0[3] + (float)v1[3]) + ((float)v2[3] + (float)v3[3]);
    }
    for (; e < e1; ++e) {
        int s = colsrc[e];
        half4 v = *(const half4*)&x[(size_t)s * 128 + lane * 4];
        ax += (float)v[0]; ay += (float)v[1]; az += (float)v[2]; aw += (float)v[3];
    }
    half4 o; o[0] = (h16)ax; o[1] = (h16)ay; o[2] = (h16)az; o[3] = (h16)aw;
    *(half4*)&agg[(size_t)nid * 128 + lane * 4] = o;
}

// ---------------- MFMA GraphConv: hpre = xin@W0 + agg@W1 + bias (+ BN stats) ----------------
// 128x128 tile/block, 4 waves; wave w: m-blocks (w&1)*2+{0,1}, n-blocks (w>>1)*2+{0,1} (32x32 tiles).
// A fp16 (exact); W split fp16 hi/lo pre-transposed [n][k] -> 2 MFMAs per product (fp32-class).
// LDS fragment-order layout: unit u = (2c+h)*128 + row, lane-consecutive => conflict-free.
__global__ __launch_bounds__(256) void k_convm(
    const h16* __restrict__ xin, const h16* __restrict__ agg,
    const h16* __restrict__ wt0, const h16* __restrict__ wt1,
    const float* __restrict__ bias,
    h16* __restrict__ hpre, float* __restrict__ colsum, float* __restrict__ colsq)
{
    __shared__ h16 lsA[4096];    // 512 units x 16B = 8KB
    __shared__ h16 lsBh[4096];
    __shared__ h16 lsBl[4096];
    __shared__ float csum[128], csq[128];
    const int tid = threadIdx.x;
    const size_t row0 = (size_t)blockIdx.x * 128;
    if (tid < 128) { csum[tid] = 0.f; csq[tid] = 0.f; }
    const int w = tid >> 6, lane = tid & 63, lm = lane & 31, lh = lane >> 5;
    const int mbase = (w & 1) * 64, nbase = (w >> 1) * 64;
    f32x16 acc[2][2];
    #pragma unroll
    for (int mi = 0; mi < 2; ++mi)
        #pragma unroll
        for (int ni = 0; ni < 2; ++ni)
            #pragma unroll
            for (int r = 0; r < 16; ++r) acc[mi][ni][r] = 0.f;

    for (int p = 0; p < 2; ++p) {
        const h16* A  = p ? agg : xin;
        const h16* Bh = p ? wt1 : wt0;
        const h16* Bl = Bh + 16384;
        for (int kc = 0; kc < 4; ++kc) {
            __syncthreads();
            #pragma unroll
            for (int it = 0; it < 2; ++it) {
                int u = tid + it * 256;
                int m = u & 127, ch = u >> 7;
                *(half8*)&lsA[u * 8]  = *(const half8*)&A[(row0 + m) * 128 + kc * 32 + ch * 8];
                *(half8*)&lsBh[u * 8] = *(const half8*)&Bh[(size_t)m * 128 + kc * 32 + ch * 8];
                *(half8*)&lsBl[u * 8] = *(const half8*)&Bl[(size_t)m * 128 + kc * 32 + ch * 8];
            }
            __syncthreads();
            #pragma unroll
            for (int c = 0; c < 2; ++c) {
                const int base = (2 * c + lh) * 128;
                half8 a0  = *(half8*)&lsA[(base + mbase + lm) * 8];
                half8 a1  = *(half8*)&lsA[(base + mbase + 32 + lm) * 8];
                half8 bh0 = *(half8*)&lsBh[(base + nbase + lm) * 8];
                half8 bh1 = *(half8*)&lsBh[(base + nbase + 32 + lm) * 8];
                half8 bl0 = *(half8*)&lsBl[(base + nbase + lm) * 8];
                half8 bl1 = *(half8*)&lsBl[(base + nbase + 32 + lm) * 8];
                acc[0][0] = __builtin_amdgcn_mfma_f32_32x32x16_f16(a0, bh0, acc[0][0], 0, 0, 0);
                acc[0][0] = __builtin_amdgcn_mfma_f32_32x32x16_f16(a0, bl0, acc[0][0], 0, 0, 0);
                acc[0][1] = __builtin_amdgcn_mfma_f32_32x32x16_f16(a0, bh1, acc[0][1], 0, 0, 0);
                acc[0][1] = __builtin_amdgcn_mfma_f32_32x32x16_f16(a0, bl1, acc[0][1], 0, 0, 0);
                acc[1][0] = __builtin_amdgcn_mfma_f32_32x32x16_f16(a1, bh0, acc[1][0], 0, 0, 0);
                acc[1][0] = __builtin_amdgcn_mfma_f32_32x32x16_f16(a1, bl0, acc[1][0], 0, 0, 0);
                acc[1][1] = __builtin_amdgcn_mfma_f32_32x32x16_f16(a1, bh1, acc[1][1], 0, 0, 0);
                acc[1][1] = __builtin_amdgcn_mfma_f32_32x32x16_f16(a1, bl1, acc[1][1], 0, 0, 0);
            }
        }
    }
    // epilogue: bias, fp16 store, BN stats
    #pragma unroll
    for (int ni = 0; ni < 2; ++ni) {
        int col = nbase + ni * 32 + lm;
        float bcol = bias[col];
        float s = 0.f, q = 0.f;
        #pragma unroll
        for (int mi = 0; mi < 2; ++mi) {
            #pragma unroll
            for (int r = 0; r < 16; ++r) {
                int row = mbase + mi * 32 + (r & 3) + 8 * (r >> 2) + 4 * lh;
                float o = acc[mi][ni][r] + bcol;
                hpre[(row0 + row) * 128 + col] = (h16)o;
                s += o; q += o * o;
            }
        }
        atomicAdd(&csum[col], s);
        atomicAdd(&csq[col], q);
    }
    __syncthreads();
    if (tid < 128) atomicAdd(&colsum[tid], csum[tid]);
    else           atomicAdd(&colsq[tid - 128], csq[tid - 128]);
}

// ---------------- q/k GEMM + bias (fp32, tiny) ; blockIdx.y selects q vs k ----------------
__global__ __launch_bounds__(256) void k_gemm_qk(
    const float* __restrict__ xin,
    const float* __restrict__ Wq, const float* __restrict__ bq, float* __restrict__ qout,
    const float* __restrict__ Wk, const float* __restrict__ bk, float* __restrict__ kout)
{
    const float* W = blockIdx.y ? Wk : Wq;
    const float* bias = blockIdx.y ? bk : bq;
    float* out = blockIdx.y ? kout : qout;
    __shared__ float xs[32][132];
    __shared__ float wcs[32][128];
    const int tid = threadIdx.x;
    const int row0 = blockIdx.x * 32;
    for (int i = tid; i < 32 * 32; i += 256) {
        int r = i >> 5, c4 = (i & 31) * 4;
        *(float4*)&xs[r][c4] = *(const float4*)&xin[(size_t)(row0 + r) * 128 + c4];
    }
    const int cg = tid & 31, rg = tid >> 5;
    float acc[4][4];
    #pragma unroll
    for (int r = 0; r < 4; ++r)
        #pragma unroll
        for (int c = 0; c < 4; ++c) acc[r][c] = 0.f;
    for (int kc = 0; kc < 4; ++kc) {
        __syncthreads();
        for (int i = tid; i < 32 * 32; i += 256) {
            int k = i >> 5, c4 = (i & 31) * 4;
            *(float4*)&wcs[k][c4] = *(const float4*)&W[(kc * 32 + k) * 128 + c4];
        }
        __syncthreads();
        #pragma unroll
        for (int k4 = 0; k4 < 8; ++k4) {
            float4 xv[4];
            #pragma unroll
            for (int r = 0; r < 4; ++r)
                xv[r] = *(float4*)&xs[rg * 4 + r][kc * 32 + k4 * 4];
            #pragma unroll
            for (int kk = 0; kk < 4; ++kk) {
                float4 w1 = *(float4*)&wcs[k4 * 4 + kk][cg * 4];
                #pragma unroll
                for (int r = 0; r < 4; ++r) {
                    float xk = (&xv[r].x)[kk];
                    acc[r][0] += xk * w1.x;
                    acc[r][1] += xk * w1.y;
                    acc[r][2] += xk * w1.z;
                    acc[r][3] += xk * w1.w;
                }
            }
        }
    }
    const float4 b4 = *(const float4*)&bias[cg * 4];
    #pragma unroll
    for (int r = 0; r < 4; ++r) {
        float4 o;
        o.x = acc[r][0] + b4.x; o.y = acc[r][1] + b4.y;
        o.z = acc[r][2] + b4.z; o.w = acc[r][3] + b4.w;
        *(float4*)&out[(size_t)(row0 + rg * 4 + r) * 128 + cg * 4] = o;
    }
}

// ---------------- per-graph MHA: scores -> softmax -> head-mean ----------------
__global__ __launch_bounds__(128) void k_attention(const float* __restrict__ q, const float* __restrict__ kmat,
                                                   float* __restrict__ attn, float* __restrict__ heat)
{
    int g = blockIdx.x, tid = threadIdx.x;
    __shared__ float qs[32][128];
    __shared__ float ks[32][128];
    __shared__ float attn_s[1024];
    for (int i = tid; i < 32 * 32; i += 128) {
        int r = i >> 5, c4 = (i & 31) * 4;
        *(float4*)&qs[r][c4] = *(const float4*)&q[((size_t)g * 32 + r) * 128 + c4];
        *(float4*)&ks[r][c4] = *(const float4*)&kmat[((size_t)g * 32 + r) * 128 + c4];
    }
    for (int i = tid; i < 1024; i += 128) attn_s[i] = 0.f;
    __syncthreads();
    int h = tid >> 5, i = tid & 31;
    float qreg[32];
    #pragma unroll
    for (int d = 0; d < 32; ++d) qreg[d] = qs[i][h * 32 + d];
    float sc[32];
    const float scale = 0.17677669529663687f;
    float mx = -1e30f;
    #pragma unroll
    for (int j = 0; j < 32; ++j) {
        float d = 0.f;
        #pragma unroll
        for (int d0 = 0; d0 < 32; ++d0) d += qreg[d0] * ks[j][h * 32 + d0];
        d *= scale;
        sc[j] = d;
        mx = fmaxf(mx, d);
    }
    float ssum = 0.f;
    #pragma unroll
    for (int j = 0; j < 32; ++j) { float e = __expf(sc[j] - mx); sc[j] = e; ssum += e; }
    float inv = 0.25f / ssum;
    #pragma unroll
    for (int j = 0; j < 32; ++j) atomicAdd(&attn_s[i * 32 + j], sc[j] * inv);
    __syncthreads();
    for (int idx = tid; idx < 1024; idx += 128) {
        float v = attn_s[idx];
        attn[(size_t)g * 1024 + idx] = v;
        if (heat != nullptr && g == 127) heat[idx] = v;
    }
}

// ---------------- x_atten[g,n] = sum_s attn[g,s,n] * x[g,s,n]  (fp16 x) ----------------
__global__ void k_xatten(const h16* __restrict__ x, const float* __restrict__ attn, h16* __restrict__ xat) {
    int gn = blockIdx.x; int g = gn >> 5, n = gn & 31;
    int c = threadIdx.x;
    __shared__ float a_s[32];
    if (c < 32) a_s[c] = attn[(size_t)g * 1024 + c * 32 + n];
    __syncthreads();
    float s = 0.f;
    #pragma unroll
    for (int s2 = 0; s2 < 32; ++s2)
        s += a_s[s2] * (float)x[(((size_t)g * 32 + s2) * 32 + n) * 128 + c];
    xat[(size_t)gn * 128 + c] = (h16)s;
}

// ---------------- x = relu(BN1(h1)+BN2(h2)); fused BN-finalize + next submean ----------------
__global__ __launch_bounds__(256) void k_update(
    const h16* __restrict__ hpre, const h16* __restrict__ h2pre,
    const float* __restrict__ stats,
    const float* __restrict__ g1, const float* __restrict__ be1,
    const float* __restrict__ g2, const float* __restrict__ be2,
    h16* __restrict__ x, float* __restrict__ sub)
{
    __shared__ float sA[128], hA[128], sB[128], hB[128];
    __shared__ float red[8][132];
    int gs = blockIdx.x, g = gs >> 5, tid = threadIdx.x;
    if (tid < 128) {
        float mu = stats[tid] * (1.f / T_);
        float var = stats[128 + tid] * (1.f / T_) - mu * mu;
        float sc = g1[tid] * rsqrtf(var + 1e-5f);
        sA[tid] = sc; hA[tid] = be1[tid] - mu * sc;
    } else {
        int c = tid - 128;
        float mu = stats[256 + c] * (1.f / TO_);
        float var = stats[384 + c] * (1.f / TO_) - mu * mu;
        float sc = g2[c] * rsqrtf(var + 1e-5f);
        sB[c] = sc; hB[c] = be2[c] - mu * sc;
    }
    __syncthreads();
    int cg = tid & 31, ng = tid >> 5;
    int c4 = cg * 4;
    float4 ssum = make_float4(0.f, 0.f, 0.f, 0.f);
    for (int n = ng; n < 32; n += 8) {
        size_t t = (size_t)gs * 32 + n;
        half4 h1v = *(const half4*)&hpre[t * 128 + c4];
        half4 h2v = *(const half4*)&h2pre[((size_t)g * 32 + n) * 128 + c4];
        float o0 = fmaxf((float)h1v[0] * sA[c4+0] + hA[c4+0] + (float)h2v[0] * sB[c4+0] + hB[c4+0], 0.f);
        float o1 = fmaxf((float)h1v[1] * sA[c4+1] + hA[c4+1] + (float)h2v[1] * sB[c4+1] + hB[c4+1], 0.f);
        float o2 = fmaxf((float)h1v[2] * sA[c4+2] + hA[c4+2] + (float)h2v[2] * sB[c4+2] + hB[c4+2], 0.f);
        float o3 = fmaxf((float)h1v[3] * sA[c4+3] + hA[c4+3] + (float)h2v[3] * sB[c4+3] + hB[c4+3], 0.f);
        half4 o; o[0] = (h16)o0; o[1] = (h16)o1; o[2] = (h16)o2; o[3] = (h16)o3;
        *(half4*)&x[t * 128 + c4] = o;
        ssum.x += o0; ssum.y += o1; ssum.z += o2; ssum.w += o3;
    }
    *(float4*)&red[ng][c4] = ssum;
    __syncthreads();
    if (ng == 0) {
        float4 s = make_float4(0.f, 0.f, 0.f, 0.f);
        #pragma unroll
        for (int r = 0; r < 8; ++r) {
            float4 v = *(float4*)&red[r][c4];
            s.x += v.x; s.y += v.y; s.z += v.z; s.w += v.w;
        }
        const float inv = 1.f / 32.f;
        s.x *= inv; s.y *= inv; s.z *= inv; s.w *= inv;
        *(float4*)&sub[(size_t)gs * 128 + c4] = s;
    }
}

// ---------------- final head: graph mean over sub + 2-layer MLP ----------------
__global__ __launch_bounds__(256) void k_dense(const float* __restrict__ sub, const float* __restrict__ Wf1,
    const float* __restrict__ bf1, const float* __restrict__ Wf2, const float* __restrict__ bf2,
    float* __restrict__ out)
{
    int g = blockIdx.x, tid = threadIdx.x;
    __shared__ float hgs[128];
    __shared__ float hid[256];
    if (tid < 128) {
        float s = 0.f;
        for (int ss = 0; ss < 32; ++ss) s += sub[((size_t)g * 32 + ss) * 128 + tid];
        hgs[tid] = s * (1.f / 32.f);
    }
    __syncthreads();
    float a = bf1[tid];
    for (int k = 0; k < 128; ++k) a += hgs[k] * Wf1[k * 256 + tid];
    hid[tid] = fmaxf(a, 0.f);
    __syncthreads();
    if (tid < 10) {
        float o = bf2[tid];
        for (int k = 0; k < 256; ++k) o += hid[k] * Wf2[k * 10 + tid];
        out[g * 10 + tid] = o;
    }
}

extern "C" void kernel_launch(void* const* d_in, const int* in_sizes, int n_in,
                              void* d_out, int out_size, void* d_ws, size_t ws_size,
                              hipStream_t stream)
{
    (void)in_sizes; (void)n_in; (void)out_size; (void)ws_size;
    const float* x0  = (const float*)d_in[0];
    const int*   ei  = (const int*)d_in[1];
    const int*   oei = (const int*)d_in[2];
    const float* Wr1 = (const float*)d_in[3];
    const float* Wn1 = (const float*)d_in[4];
    const float* b1  = (const float*)d_in[5];
    const float* g1  = (const float*)d_in[6];
    const float* be1 = (const float*)d_in[7];
    const float* Wr2 = (const float*)d_in[8];
    const float* Wn2 = (const float*)d_in[9];
    const float* b2  = (const float*)d_in[10];
    const float* g2  = (const float*)d_in[11];
    const float* be2 = (const float*)d_in[12];
    const float* Wq  = (const float*)d_in[13];
    const float* bq  = (const float*)d_in[14];
    const float* Wk  = (const float*)d_in[15];
    const float* bk  = (const float*)d_in[16];
    const float* Wf1 = (const float*)d_in[17];
    const float* bf1 = (const float*)d_in[18];
    const float* Wf2 = (const float*)d_in[19];
    const float* bf2 = (const float*)d_in[20];
    float* out = (float*)d_out;

    char* w = (char*)d_ws;
    size_t off = 0;
    auto alloc = [&](size_t bytes) { void* p = w + off; off = (off + bytes + 255) & ~(size_t)255; return p; };
    h16* xh     = (h16*)alloc((size_t)T_ * D_ * 2);
    h16* aggh   = (h16*)alloc((size_t)T_ * D_ * 2);   // aliased as h1pre (block-local RAW safe)
    h16* agg2   = (h16*)alloc((size_t)TO_ * D_ * 2);  // aliased as h2pre
    h16* xat    = (h16*)alloc((size_t)TO_ * D_ * 2);
    h16* wt     = (h16*)alloc((size_t)12 * 2 * 16384 * 2);
    float* sub    = (float*)alloc((size_t)G_ * S_ * D_ * 4);
    float* qbuf   = (float*)alloc((size_t)G_ * S_ * D_ * 4);
    float* kbuf   = (float*)alloc((size_t)G_ * S_ * D_ * 4);
    float* attnb  = (float*)alloc((size_t)G_ * S_ * S_ * 4);
    float* stats  = (float*)alloc(512 * 4);           // sumA sqA sumB sqB
    int* rowptr  = (int*)alloc((T_ + 1) * 4);
    int* deg     = (int*)alloc(T_ * 4);
    int* incl    = (int*)alloc(T_ * 4);
    int* bsum    = (int*)alloc(512 * 4);
    int* bexcl   = (int*)alloc(512 * 4);
    int* cursor  = (int*)alloc(T_ * 4);
    int* colsrc  = (int*)alloc((size_t)E_ * 4);
    int* orowptr = (int*)alloc((TO_ + 1) * 4);
    int* odeg    = (int*)alloc(TO_ * 4);
    int* oincl   = (int*)alloc(TO_ * 4);
    int* obsum   = (int*)alloc(512 * 4);
    int* obexcl  = (int*)alloc(512 * 4);
    int* ocursor = (int*)alloc(TO_ * 4);
    int* ocolsrc = (int*)alloc((size_t)EO_ * 4);

    h16* h1pre = aggh;
    h16* h2pre = agg2;
    float* sumA = stats + 0,  *sqA = stats + 128;
    float* sumB = stats + 256, *sqB = stats + 384;

    hipMemsetAsync(deg, 0, (size_t)T_ * 4, stream);
    hipMemsetAsync(odeg, 0, (size_t)TO_ * 4, stream);

    k_hist<<<E_ / 256, 256, 0, stream>>>(ei + E_, deg, E_);
    k_scan1<<<T_ / 256, 256, 0, stream>>>(deg, incl, bsum, T_);
    k_scan2<<<1, 512, 0, stream>>>(bsum, bexcl, T_ / 256);
    k_scan3<<<T_ / 256, 256, 0, stream>>>(incl, bexcl, rowptr, T_);
    k_copyint<<<T_ / 256, 256, 0, stream>>>(rowptr, cursor, T_);
    k_fill<<<E_ / 256, 256, 0, stream>>>(ei, ei + E_, cursor, colsrc, E_);
    k_hist<<<EO_ / 256, 256, 0, stream>>>(oei + EO_, odeg, EO_);
    k_scan1<<<TO_ / 256, 256, 0, stream>>>(odeg, oincl, obsum, TO_);
    k_scan2<<<1, 512, 0, stream>>>(obsum, obexcl, TO_ / 256);
    k_scan3<<<TO_ / 256, 256, 0, stream>>>(oincl, obexcl, orowptr, TO_);
    k_copyint<<<TO_ / 256, 256, 0, stream>>>(orowptr, ocursor, TO_);
    k_fill<<<EO_ / 256, 256, 0, stream>>>(oei, oei + EO_, ocursor, ocolsrc, EO_);

    k_prepw<<<dim3(12, 16), 256, 0, stream>>>(Wr1, Wn1, Wr2, Wn2, wt);
    k_tohalf_sub<<<G_ * S_, 256, 0, stream>>>(x0, xh, sub);

    for (int i = 0; i < 3; ++i) {
        hipMemsetAsync(stats, 0, 512 * 4, stream);
        k_agg<<<T_ / 8, 256, 0, stream>>>(xh, rowptr, colsrc, aggh, T_);
        k_convm<<<T_ / 128, 256, 0, stream>>>(xh, aggh,
            wt + (size_t)(0 * 3 + i) * 2 * 16384, wt + (size_t)(1 * 3 + i) * 2 * 16384,
            b1 + i * D_, h1pre, sumA, sqA);
        k_gemm_qk<<<dim3((G_ * S_) / 32, 2), 256, 0, stream>>>(sub,
            Wq + (size_t)i * D_ * D_, bq + i * D_, qbuf,
            Wk + (size_t)i * D_ * D_, bk + i * D_, kbuf);
        k_attention<<<G_, 128, 0, stream>>>(qbuf, kbuf, attnb, (i == 2) ? (out + G_ * NTASK_) : nullptr);
        k_xatten<<<G_ * N_, 128, 0, stream>>>(xh, attnb, xat);
        k_agg<<<TO_ / 8, 256, 0, stream>>>(xat, orowptr, ocolsrc, agg2, TO_);
        k_convm<<<TO_ / 128, 256, 0, stream>>>(xat, agg2,
            wt + (size_t)(2 * 3 + i) * 2 * 16384, wt + (size_t)(3 * 3 + i) * 2 * 16384,
            b2 + i * D_, h2pre, sumB, sqB);
        k_update<<<G_ * S_, 256, 0, stream>>>(h1pre, h2pre, stats,
            g1 + i * D_, be1 + i * D_, g2 + i * D_, be2 + i * D_, xh, sub);
    }
    k_dense<<<G_, 256, 0, stream>>>(sub, Wf1, bf1, Wf2, bf2, out);
}

// Round 4
// 817.008 us; speedup vs baseline: 3.2237x; 1.0029x over previous
//
#include <hip/hip_runtime.h>

#define G_   128
#define S_   32
#define N_   32
#define D_   128
#define T_   (G_*S_*N_)    // 131072
#define TO_  (G_*N_)       // 4096
#define E_   1048576
#define EO_  16384
#define NTASK_ 10

typedef _Float16 h16;
typedef _Float16 half8 __attribute__((ext_vector_type(8)));
typedef _Float16 half4 __attribute__((ext_vector_type(4)));
typedef float f32x16 __attribute__((ext_vector_type(16)));

// ================= merged setup: hist(E+EO) | conv-weight split prep | qk fp16 prep | x->fp16 + submean =================
// grid: [0,4160) hist ; [4160,4352) conv W prep (12 mats x 16 chunks) ; [4352,4448) qk W prep (6 x 16) ; [4448,8544) tohalf_sub
__global__ __launch_bounds__(256) void k_prep(
    const int* __restrict__ ei, const int* __restrict__ oei,
    const float* __restrict__ Wr1, const float* __restrict__ Wn1,
    const float* __restrict__ Wr2, const float* __restrict__ Wn2,
    const float* __restrict__ Wq, const float* __restrict__ Wk,
    const float* __restrict__ x0,
    int* __restrict__ deg, int* __restrict__ odeg,
    h16* __restrict__ wt, h16* __restrict__ wqkt,
    h16* __restrict__ xh, h16* __restrict__ subh)
{
    __shared__ float red[8][132];
    int b = blockIdx.x, t = threadIdx.x;
    if (b < 4160) {
        int e = b * 256 + t;
        if (e < E_) atomicAdd(&deg[ei[E_ + e]], 1);
        else        atomicAdd(&odeg[oei[EO_ + (e - E_)]], 1);
    } else if (b < 4352) {
        int idx = b - 4160, mat = idx >> 4, chunk = idx & 15;
        int arr = mat / 3, layer = mat % 3;
        const float* W = (arr == 0 ? Wr1 : arr == 1 ? Wn1 : arr == 2 ? Wr2 : Wn2) + (size_t)layer * 16384;
        h16* outh = wt + (size_t)mat * 32768;
        h16* outl = outh + 16384;
        int base = chunk * 1024;
        for (int i = t; i < 1024; i += 256) {
            int id = base + i;
            int k = id >> 7, n = id & 127;
            float v = W[id];
            h16 hi = (h16)v;
            h16 lo = (h16)(v - (float)hi);
            outh[n * 128 + k] = hi;
            outl[n * 128 + k] = lo;
        }
    } else if (b < 4448) {
        int idx = b - 4352, m = idx >> 4, chunk = idx & 15;
        int layer = m >> 1, which = m & 1;
        const float* W = (which ? Wk : Wq) + (size_t)layer * 16384;
        h16* o = wqkt + (size_t)m * 16384;
        int base = chunk * 1024;
        for (int i = t; i < 1024; i += 256) {
            int id = base + i;
            int k = id >> 7, n = id & 127;
            o[n * 128 + k] = (h16)W[id];
        }
    } else {
        int gs = b - 4448;
        int cg = t & 31, rg = t >> 5;
        int c4 = cg * 4;
        float4 ssum = make_float4(0.f, 0.f, 0.f, 0.f);
        for (int n = rg; n < 32; n += 8) {
            size_t tt = (size_t)gs * 32 + n;
            float4 v = *(const float4*)&x0[tt * 128 + c4];
            half4 o; o[0] = (h16)v.x; o[1] = (h16)v.y; o[2] = (h16)v.z; o[3] = (h16)v.w;
            *(half4*)&xh[tt * 128 + c4] = o;
            ssum.x += v.x; ssum.y += v.y; ssum.z += v.z; ssum.w += v.w;
        }
        *(float4*)&red[rg][c4] = ssum;
        __syncthreads();
        if (rg == 0) {
            float4 s = make_float4(0.f, 0.f, 0.f, 0.f);
            #pragma unroll
            for (int r = 0; r < 8; ++r) {
                float4 v = *(float4*)&red[r][c4];
                s.x += v.x; s.y += v.y; s.z += v.z; s.w += v.w;
            }
            const float inv = 1.f / 32.f;
            half4 o; o[0] = (h16)(s.x*inv); o[1] = (h16)(s.y*inv); o[2] = (h16)(s.z*inv); o[3] = (h16)(s.w*inv);
            *(half4*)&subh[(size_t)gs * 128 + c4] = o;
        }
    }
}

// ================= merged scans =================
__global__ void k_scan1m(const int* __restrict__ deg, int* __restrict__ incl, int* __restrict__ bsum,
                         const int* __restrict__ odeg, int* __restrict__ oincl, int* __restrict__ obsum)
{
    __shared__ int tmp[256];
    int b = blockIdx.x;
    const int* in; int* out; int* bs; int bloc;
    if (b < 512) { in = deg;  out = incl;  bs = bsum;  bloc = b; }
    else         { in = odeg; out = oincl; bs = obsum; bloc = b - 512; }
    int i = bloc * 256 + threadIdx.x;
    tmp[threadIdx.x] = in[i];
    __syncthreads();
    for (int off = 1; off < 256; off <<= 1) {
        int v = (threadIdx.x >= off) ? tmp[threadIdx.x - off] : 0;
        __syncthreads();
        tmp[threadIdx.x] += v;
        __syncthreads();
    }
    out[i] = tmp[threadIdx.x];
    if (threadIdx.x == 255) bs[bloc] = tmp[255];
}

__global__ void k_scan2m(const int* __restrict__ bsum, int* __restrict__ bexcl,
                         const int* __restrict__ obsum, int* __restrict__ obexcl)
{
    __shared__ int tmp[512];
    int t = threadIdx.x;
    const int* arr; int* out; int nb;
    if (blockIdx.x == 0) { arr = bsum; out = bexcl; nb = 512; }
    else                 { arr = obsum; out = obexcl; nb = 16; }
    int v = (t < nb) ? arr[t] : 0;
    tmp[t] = v;
    __syncthreads();
    for (int off = 1; off < 512; off <<= 1) {
        int u = (t >= off) ? tmp[t - off] : 0;
        __syncthreads();
        tmp[t] += u;
        __syncthreads();
    }
    if (t < nb) out[t] = tmp[t] - v;
}

__global__ void k_scan3m(const int* __restrict__ incl, const int* __restrict__ bexcl,
                         int* __restrict__ rowptr, int* __restrict__ cursor, const int* __restrict__ deg,
                         const int* __restrict__ oincl, const int* __restrict__ obexcl,
                         int* __restrict__ orowptr, int* __restrict__ ocursor, const int* __restrict__ odeg)
{
    int b = blockIdx.x;
    if (b < 512) {
        int i = b * 256 + threadIdx.x;
        int e = incl[i] + bexcl[b];
        rowptr[i + 1] = e;
        cursor[i] = e - deg[i];
        if (i == 0) rowptr[0] = 0;
    } else {
        int b2 = b - 512;
        int i = b2 * 256 + threadIdx.x;
        int e = oincl[i] + obexcl[b2];
        orowptr[i + 1] = e;
        ocursor[i] = e - odeg[i];
        if (i == 0) orowptr[0] = 0;
    }
}

// ================= partitioned CSR fill: pass p handles dst in [p*8192,(p+1)*8192) =================
// colsrc write region per pass ~256KB -> L2-resident -> full-line write coalescing. y==16: EO single pass.
__global__ __launch_bounds__(256) void k_fillp(
    const int* __restrict__ src, const int* __restrict__ dst,
    int* __restrict__ cursor, int* __restrict__ colsrc,
    const int* __restrict__ osrc, const int* __restrict__ odst,
    int* __restrict__ ocursor, int* __restrict__ ocolsrc)
{
    int p = blockIdx.y;
    if (p < 16) {
        int e0 = blockIdx.x * 1024 + threadIdx.x * 4;
        int4 d4 = *(const int4*)&dst[e0];
        #pragma unroll
        for (int j = 0; j < 4; ++j) {
            int d = (&d4.x)[j];
            if ((d >> 13) == p) {
                int s = src[e0 + j];
                int pos = atomicAdd(&cursor[d], 1);
                colsrc[pos] = s;
            }
        }
    } else {
        if (blockIdx.x >= 16) return;
        int e0 = blockIdx.x * 1024 + threadIdx.x * 4;
        int4 d4 = *(const int4*)&odst[e0];
        #pragma unroll
        for (int j = 0; j < 4; ++j) {
            int d = (&d4.x)[j];
            int s = osrc[e0 + j];
            int pos = atomicAdd(&ocursor[d], 1);
            ocolsrc[pos] = s;
        }
    }
}

// ================= merged: CSR aggregation (T) | per-graph attention megakernel =================
// blocks [0,16384): agg 8 nodes/block. blocks [16384,16512): attention for graph g (q/k MFMA -> softmax -> x_atten).
__global__ __launch_bounds__(256) void k_agg_attn(
    const h16* __restrict__ xh, const int* __restrict__ rowptr, const int* __restrict__ colsrc,
    h16* __restrict__ agg,
    const h16* __restrict__ subh, const h16* __restrict__ wqkt_l,
    const float* __restrict__ bql, const float* __restrict__ bkl,
    float* __restrict__ heat, h16* __restrict__ xat)
{
    __shared__ __align__(16) char smem[25600];
    const int tid = threadIdx.x;
    if (blockIdx.x < 16384) {
        // ---- aggregation path ----
        int nid = blockIdx.x * 8 + (tid >> 5);
        int lane = tid & 31;
        int e0 = rowptr[nid], e1 = rowptr[nid + 1];
        float ax = 0.f, ay = 0.f, az = 0.f, aw = 0.f;
        int e = e0;
        for (; e + 4 <= e1; e += 4) {
            int s0 = colsrc[e + 0], s1 = colsrc[e + 1], s2 = colsrc[e + 2], s3 = colsrc[e + 3];
            half4 v0 = *(const half4*)&xh[(size_t)s0 * 128 + lane * 4];
            half4 v1 = *(const half4*)&xh[(size_t)s1 * 128 + lane * 4];
            half4 v2 = *(const half4*)&xh[(size_t)s2 * 128 + lane * 4];
            half4 v3 = *(const half4*)&xh[(size_t)s3 * 128 + lane * 4];
            ax += ((float)v0[0] + (float)v1[0]) + ((float)v2[0] + (float)v3[0]);
            ay += ((float)v0[1] + (float)v1[1]) + ((float)v2[1] + (float)v3[1]);
            az += ((float)v0[2] + (float)v1[2]) + ((float)v2[2] + (float)v3[2]);
            aw += ((float)v0[3] + (float)v1[3]) + ((float)v2[3] + (float)v3[3]);
        }
        for (; e < e1; ++e) {
            int s = colsrc[e];
            half4 v = *(const half4*)&xh[(size_t)s * 128 + lane * 4];
            ax += (float)v[0]; ay += (float)v[1]; az += (float)v[2]; aw += (float)v[3];
        }
        half4 o; o[0] = (h16)ax; o[1] = (h16)ay; o[2] = (h16)az; o[3] = (h16)aw;
        *(half4*)&agg[(size_t)nid * 128 + lane * 4] = o;
        return;
    }
    // ---- attention path: one block per graph g ----
    const int g = blockIdx.x - 16384;
    h16* aF = (h16*)smem;                   // 512 frag units x 8 h16 = 8KB (sub in MFMA A-frag order)
    h16* qkT = (h16*)(smem + 8192);         // [mat][n(128)][34] fp16 = 17408B (channel-major q/k)
    float* attn_s = (float*)smem;           // alias over aF after GEMM phase (4KB)
    // stage sub fragments
    #pragma unroll
    for (int it = 0; it < 2; ++it) {
        int u = tid + it * 256;
        int kq = u >> 6, l = u & 63;
        int m = l & 31, ko = kq * 16 + (l >> 5) * 8;
        *(half8*)&aF[u * 8] = *(const half8*)&subh[((size_t)g * 32 + m) * 128 + ko];
    }
    __syncthreads();
    const int w = tid >> 6, lane = tid & 63, lm = lane & 31, lh = lane >> 5;
    const int mat = w & 1, ntp = (w >> 1) * 2;
    const h16* Wt = wqkt_l + (size_t)mat * 16384;
    const float* bias = mat ? bkl : bql;
    f32x16 a0, a1;
    #pragma unroll
    for (int r = 0; r < 16; ++r) { a0[r] = 0.f; a1[r] = 0.f; }
    #pragma unroll
    for (int kq = 0; kq < 8; ++kq) {
        half8 av = *(half8*)&aF[(kq * 64 + lane) * 8];
        half8 b0 = *(const half8*)&Wt[(size_t)(ntp * 32 + lm) * 128 + kq * 16 + lh * 8];
        half8 b1 = *(const half8*)&Wt[(size_t)((ntp + 1) * 32 + lm) * 128 + kq * 16 + lh * 8];
        a0 = __builtin_amdgcn_mfma_f32_32x32x16_f16(av, b0, a0, 0, 0, 0);
        a1 = __builtin_amdgcn_mfma_f32_32x32x16_f16(av, b1, a1, 0, 0, 0);
    }
    __syncthreads();   // aF reads done by all -> safe to alias as attn_s later
    #pragma unroll
    for (int ti = 0; ti < 2; ++ti) {
        int n = (ntp + ti) * 32 + lm;
        float bn = bias[n];
        #pragma unroll
        for (int r = 0; r < 16; ++r) {
            int s = (r & 3) + 8 * (r >> 2) + 4 * lh;
            float v = (ti ? a1[r] : a0[r]) + bn;
            qkT[(mat * 128 + n) * 34 + s] = (h16)v;
        }
    }
    for (int i = tid; i < 1024; i += 256) attn_s[i] = 0.f;
    __syncthreads();
    if (tid < 128) {
        int h = tid >> 5, i = tid & 31;
        float qreg[32];
        #pragma unroll
        for (int d = 0; d < 32; ++d) qreg[d] = (float)qkT[(h * 32 + d) * 34 + i];
        float sc[32];
        const float scale = 0.17677669529663687f; // 1/sqrt(32)
        float mx = -1e30f;
        #pragma unroll
        for (int j = 0; j < 32; ++j) {
            float d = 0.f;
            #pragma unroll
            for (int d0 = 0; d0 < 32; ++d0) d += qreg[d0] * (float)qkT[(128 + h * 32 + d0) * 34 + j];
            d *= scale;
            sc[j] = d;
            mx = fmaxf(mx, d);
        }
        float ssum = 0.f;
        #pragma unroll
        for (int j = 0; j < 32; ++j) { float ee = __expf(sc[j] - mx); sc[j] = ee; ssum += ee; }
        float inv = 0.25f / ssum;  // head-mean folded in
        #pragma unroll
        for (int j = 0; j < 32; ++j) atomicAdd(&attn_s[i * 32 + j], sc[j] * inv);
    }
    __syncthreads();
    if (heat != nullptr && g == 127) {
        for (int idx = tid; idx < 1024; idx += 256) heat[idx] = attn_s[idx];
    }
    // x_atten for this g
    {
        int c4 = (tid & 31) * 4;
        int ng = tid >> 5;
        for (int n = ng; n < 32; n += 8) {
            float ax = 0.f, ay = 0.f, az = 0.f, aw = 0.f;
            #pragma unroll
            for (int s = 0; s < 32; ++s) {
                float a = attn_s[s * 32 + n];
                half4 xv = *(const half4*)&xh[(((size_t)g * 32 + s) * 32 + n) * 128 + c4];
                ax += a * (float)xv[0]; ay += a * (float)xv[1];
                az += a * (float)xv[2]; aw += a * (float)xv[3];
            }
            half4 o; o[0] = (h16)ax; o[1] = (h16)ay; o[2] = (h16)az; o[3] = (h16)aw;
            *(half4*)&xat[((size_t)g * 32 + n) * 128 + c4] = o;
        }
    }
}

// ================= CSR aggregation for original graph (small) =================
__global__ __launch_bounds__(256) void k_aggo(
    const h16* __restrict__ x, const int* __restrict__ rowptr, const int* __restrict__ colsrc,
    h16* __restrict__ agg)
{
    int nid = blockIdx.x * 8 + (threadIdx.x >> 5);
    int lane = threadIdx.x & 31;
    int e0 = rowptr[nid], e1 = rowptr[nid + 1];
    float ax = 0.f, ay = 0.f, az = 0.f, aw = 0.f;
    int e = e0;
    for (; e + 4 <= e1; e += 4) {
        int s0 = colsrc[e + 0], s1 = colsrc[e + 1], s2 = colsrc[e + 2], s3 = colsrc[e + 3];
        half4 v0 = *(const half4*)&x[(size_t)s0 * 128 + lane * 4];
        half4 v1 = *(const half4*)&x[(size_t)s1 * 128 + lane * 4];
        half4 v2 = *(const half4*)&x[(size_t)s2 * 128 + lane * 4];
        half4 v3 = *(const half4*)&x[(size_t)s3 * 128 + lane * 4];
        ax += ((float)v0[0] + (float)v1[0]) + ((float)v2[0] + (float)v3[0]);
        ay += ((float)v0[1] + (float)v1[1]) + ((float)v2[1] + (float)v3[1]);
        az += ((float)v0[2] + (float)v1[2]) + ((float)v2[2] + (float)v3[2]);
        aw += ((float)v0[3] + (float)v1[3]) + ((float)v2[3] + (float)v3[3]);
    }
    for (; e < e1; ++e) {
        int s = colsrc[e];
        half4 v = *(const half4*)&x[(size_t)s * 128 + lane * 4];
        ax += (float)v[0]; ay += (float)v[1]; az += (float)v[2]; aw += (float)v[3];
    }
    half4 o; o[0] = (h16)ax; o[1] = (h16)ay; o[2] = (h16)az; o[3] = (h16)aw;
    *(half4*)&agg[(size_t)nid * 128 + lane * 4] = o;
}

// ================= merged MFMA GraphConv (T branch | TO branch) + BN stats =================
// blocks [0,1024): T matmul; [1024,1056): TO matmul. 128x128 tile, split-fp16 weights (hi+lo).
__global__ __launch_bounds__(256) void k_convs(
    const h16* __restrict__ xT, const h16* __restrict__ aggT,
    const h16* __restrict__ xO, const h16* __restrict__ aggO,
    const h16* __restrict__ wt, int layer,
    const float* __restrict__ b1l, const float* __restrict__ b2l,
    h16* __restrict__ h1, h16* __restrict__ h2, float* __restrict__ stats)
{
    __shared__ h16 lsA[4096];
    __shared__ h16 lsBh[4096];
    __shared__ h16 lsBl[4096];
    __shared__ float csum[128], csq[128];
    const int tid = threadIdx.x;
    const h16 *A0, *A1, *W0, *W1; const float* bias; h16* outp; float *gsum, *gsq; size_t row0;
    if (blockIdx.x < 1024) {
        A0 = xT; A1 = aggT;
        W0 = wt + (size_t)(0 * 3 + layer) * 32768;
        W1 = wt + (size_t)(1 * 3 + layer) * 32768;
        bias = b1l; outp = h1; gsum = stats; gsq = stats + 128;
        row0 = (size_t)blockIdx.x * 128;
    } else {
        A0 = xO; A1 = aggO;
        W0 = wt + (size_t)(2 * 3 + layer) * 32768;
        W1 = wt + (size_t)(3 * 3 + layer) * 32768;
        bias = b2l; outp = h2; gsum = stats + 256; gsq = stats + 384;
        row0 = (size_t)(blockIdx.x - 1024) * 128;
    }
    if (tid < 128) { csum[tid] = 0.f; csq[tid] = 0.f; }
    const int w = tid >> 6, lane = tid & 63, lm = lane & 31, lh = lane >> 5;
    const int mbase = (w & 1) * 64, nbase = (w >> 1) * 64;
    f32x16 acc[2][2];
    #pragma unroll
    for (int mi = 0; mi < 2; ++mi)
        #pragma unroll
        for (int ni = 0; ni < 2; ++ni)
            #pragma unroll
            for (int r = 0; r < 16; ++r) acc[mi][ni][r] = 0.f;

    for (int p = 0; p < 2; ++p) {
        const h16* A  = p ? A1 : A0;
        const h16* Bh = p ? W1 : W0;
        const h16* Bl = Bh + 16384;
        for (int kc = 0; kc < 4; ++kc) {
            __syncthreads();
            #pragma unroll
            for (int it = 0; it < 2; ++it) {
                int u = tid + it * 256;
                int m = u & 127, ch = u >> 7;
                *(half8*)&lsA[u * 8]  = *(const half8*)&A[(row0 + m) * 128 + kc * 32 + ch * 8];
                *(half8*)&lsBh[u * 8] = *(const half8*)&Bh[(size_t)m * 128 + kc * 32 + ch * 8];
                *(half8*)&lsBl[u * 8] = *(const half8*)&Bl[(size_t)m * 128 + kc * 32 + ch * 8];
            }
            __syncthreads();
            #pragma unroll
            for (int c = 0; c < 2; ++c) {
                const int base = (2 * c + lh) * 128;
                half8 a0  = *(half8*)&lsA[(base + mbase + lm) * 8];
                half8 a1  = *(half8*)&lsA[(base + mbase + 32 + lm) * 8];
                half8 bh0 = *(half8*)&lsBh[(base + nbase + lm) * 8];
                half8 bh1 = *(half8*)&lsBh[(base + nbase + 32 + lm) * 8];
                half8 bl0 = *(half8*)&lsBl[(base + nbase + lm) * 8];
                half8 bl1 = *(half8*)&lsBl[(base + nbase + 32 + lm) * 8];
                acc[0][0] = __builtin_amdgcn_mfma_f32_32x32x16_f16(a0, bh0, acc[0][0], 0, 0, 0);
                acc[0][0] = __builtin_amdgcn_mfma_f32_32x32x16_f16(a0, bl0, acc[0][0], 0, 0, 0);
                acc[0][1] = __builtin_amdgcn_mfma_f32_32x32x16_f16(a0, bh1, acc[0][1], 0, 0, 0);
                acc[0][1] = __builtin_amdgcn_mfma_f32_32x32x16_f16(a0, bl1, acc[0][1], 0, 0, 0);
                acc[1][0] = __builtin_amdgcn_mfma_f32_32x32x16_f16(a1, bh0, acc[1][0], 0, 0, 0);
                acc[1][0] = __builtin_amdgcn_mfma_f32_32x32x16_f16(a1, bl0, acc[1][0], 0, 0, 0);
                acc[1][1] = __builtin_amdgcn_mfma_f32_32x32x16_f16(a1, bh1, acc[1][1], 0, 0, 0);
                acc[1][1] = __builtin_amdgcn_mfma_f32_32x32x16_f16(a1, bl1, acc[1][1], 0, 0, 0);
            }
        }
    }
    #pragma unroll
    for (int ni = 0; ni < 2; ++ni) {
        int col = nbase + ni * 32 + lm;
        float bcol = bias[col];
        float s = 0.f, q = 0.f;
        #pragma unroll
        for (int mi = 0; mi < 2; ++mi) {
            #pragma unroll
            for (int r = 0; r < 16; ++r) {
                int row = mbase + mi * 32 + (r & 3) + 8 * (r >> 2) + 4 * lh;
                float o = acc[mi][ni][r] + bcol;
                outp[(row0 + row) * 128 + col] = (h16)o;
                s += o; q += o * o;
            }
        }
        atomicAdd(&csum[col], s);
        atomicAdd(&csq[col], q);
    }
    __syncthreads();
    if (tid < 128) atomicAdd(&gsum[tid], csum[tid]);
    else           atomicAdd(&gsq[tid - 128], csq[tid - 128]);
}

// ================= x = relu(BN1(h1)+BN2(h2)); fused BN-finalize + next submean (fp16 sub) =================
__global__ __launch_bounds__(256) void k_update(
    const h16* __restrict__ hpre, const h16* __restrict__ h2pre,
    const float* __restrict__ stats,
    const float* __restrict__ g1, const float* __restrict__ be1,
    const float* __restrict__ g2, const float* __restrict__ be2,
    h16* __restrict__ x, h16* __restrict__ subh)
{
    __shared__ float sA[128], hA[128], sB[128], hB[128];
    __shared__ float red[8][132];
    int gs = blockIdx.x, g = gs >> 5, tid = threadIdx.x;
    if (tid < 128) {
        float mu = stats[tid] * (1.f / T_);
        float var = stats[128 + tid] * (1.f / T_) - mu * mu;
        float sc = g1[tid] * rsqrtf(var + 1e-5f);
        sA[tid] = sc; hA[tid] = be1[tid] - mu * sc;
    } else {
        int c = tid - 128;
        float mu = stats[256 + c] * (1.f / TO_);
        float var = stats[384 + c] * (1.f / TO_) - mu * mu;
        float sc = g2[c] * rsqrtf(var + 1e-5f);
        sB[c] = sc; hB[c] = be2[c] - mu * sc;
    }
    __syncthreads();
    int cg = tid & 31, ng = tid >> 5;
    int c4 = cg * 4;
    float4 ssum = make_float4(0.f, 0.f, 0.f, 0.f);
    for (int n = ng; n < 32; n += 8) {
        size_t t = (size_t)gs * 32 + n;
        half4 h1v = *(const half4*)&hpre[t * 128 + c4];
        half4 h2v = *(const half4*)&h2pre[((size_t)g * 32 + n) * 128 + c4];
        float o0 = fmaxf((float)h1v[0] * sA[c4+0] + hA[c4+0] + (float)h2v[0] * sB[c4+0] + hB[c4+0], 0.f);
        float o1 = fmaxf((float)h1v[1] * sA[c4+1] + hA[c4+1] + (float)h2v[1] * sB[c4+1] + hB[c4+1], 0.f);
        float o2 = fmaxf((float)h1v[2] * sA[c4+2] + hA[c4+2] + (float)h2v[2] * sB[c4+2] + hB[c4+2], 0.f);
        float o3 = fmaxf((float)h1v[3] * sA[c4+3] + hA[c4+3] + (float)h2v[3] * sB[c4+3] + hB[c4+3], 0.f);
        half4 o; o[0] = (h16)o0; o[1] = (h16)o1; o[2] = (h16)o2; o[3] = (h16)o3;
        *(half4*)&x[t * 128 + c4] = o;
        ssum.x += o0; ssum.y += o1; ssum.z += o2; ssum.w += o3;
    }
    *(float4*)&red[ng][c4] = ssum;
    __syncthreads();
    if (ng == 0) {
        float4 s = make_float4(0.f, 0.f, 0.f, 0.f);
        #pragma unroll
        for (int r = 0; r < 8; ++r) {
            float4 v = *(float4*)&red[r][c4];
            s.x += v.x; s.y += v.y; s.z += v.z; s.w += v.w;
        }
        const float inv = 1.f / 32.f;
        half4 o; o[0] = (h16)(s.x*inv); o[1] = (h16)(s.y*inv); o[2] = (h16)(s.z*inv); o[3] = (h16)(s.w*inv);
        *(half4*)&subh[(size_t)gs * 128 + c4] = o;
    }
}

// ================= final head =================
__global__ __launch_bounds__(256) void k_dense(const h16* __restrict__ subh, const float* __restrict__ Wf1,
    const float* __restrict__ bf1, const float* __restrict__ Wf2, const float* __restrict__ bf2,
    float* __restrict__ out)
{
    int g = blockIdx.x, tid = threadIdx.x;
    __shared__ float hgs[128];
    __shared__ float hid[256];
    if (tid < 128) {
        float s = 0.f;
        for (int ss = 0; ss < 32; ++ss) s += (float)subh[((size_t)g * 32 + ss) * 128 + tid];
        hgs[tid] = s * (1.f / 32.f);
    }
    __syncthreads();
    float a = bf1[tid];
    for (int k = 0; k < 128; ++k) a += hgs[k] * Wf1[k * 256 + tid];
    hid[tid] = fmaxf(a, 0.f);
    __syncthreads();
    if (tid < 10) {
        float o = bf2[tid];
        for (int k = 0; k < 256; ++k) o += hid[k] * Wf2[k * 10 + tid];
        out[g * 10 + tid] = o;
    }
}

extern "C" void kernel_launch(void* const* d_in, const int* in_sizes, int n_in,
                              void* d_out, int out_size, void* d_ws, size_t ws_size,
                              hipStream_t stream)
{
    (void)in_sizes; (void)n_in; (void)out_size; (void)ws_size;
    const float* x0  = (const float*)d_in[0];
    const int*   ei  = (const int*)d_in[1];
    const int*   oei = (const int*)d_in[2];
    const float* Wr1 = (const float*)d_in[3];
    const float* Wn1 = (const float*)d_in[4];
    const float* b1  = (const float*)d_in[5];
    const float* g1  = (const float*)d_in[6];
    const float* be1 = (const float*)d_in[7];
    const float* Wr2 = (const float*)d_in[8];
    const float* Wn2 = (const float*)d_in[9];
    const float* b2  = (const float*)d_in[10];
    const float* g2  = (const float*)d_in[11];
    const float* be2 = (const float*)d_in[12];
    const float* Wq  = (const float*)d_in[13];
    const float* bq  = (const float*)d_in[14];
    const float* Wk  = (const float*)d_in[15];
    const float* bk  = (const float*)d_in[16];
    const float* Wf1 = (const float*)d_in[17];
    const float* bf1 = (const float*)d_in[18];
    const float* Wf2 = (const float*)d_in[19];
    const float* bf2 = (const float*)d_in[20];
    float* out = (float*)d_out;

    char* w = (char*)d_ws;
    size_t off = 0;
    auto alloc = [&](size_t bytes) { void* p = w + off; off = (off + bytes + 255) & ~(size_t)255; return p; };
    h16* xh     = (h16*)alloc((size_t)T_ * D_ * 2);
    h16* aggh   = (h16*)alloc((size_t)T_ * D_ * 2);   // aliased as h1pre (block-local RAW safe)
    h16* agg2   = (h16*)alloc((size_t)TO_ * D_ * 2);  // aliased as h2pre
    h16* xat    = (h16*)alloc((size_t)TO_ * D_ * 2);
    h16* wt     = (h16*)alloc((size_t)12 * 32768 * 2);
    h16* wqkt   = (h16*)alloc((size_t)6 * 16384 * 2);
    h16* subh   = (h16*)alloc((size_t)G_ * S_ * D_ * 2);
    // zero-init region: deg | odeg | stats(3 layers x 512)
    int* deg     = (int*)alloc((size_t)(T_ + TO_) * 4 + 1536 * 4);
    int* odeg    = deg + T_;
    float* stats = (float*)(deg + T_ + TO_);
    int* incl    = (int*)alloc((size_t)(T_ + TO_) * 4);
    int* oincl   = incl + T_;
    int* bsum    = (int*)alloc(512 * 4);
    int* obsum   = (int*)alloc(16 * 4);
    int* bexcl   = (int*)alloc(512 * 4);
    int* obexcl  = (int*)alloc(16 * 4);
    int* rowptr  = (int*)alloc((T_ + 1) * 4);
    int* orowptr = (int*)alloc((TO_ + 1) * 4);
    int* cursor  = (int*)alloc(T_ * 4);
    int* ocursor = (int*)alloc(TO_ * 4);
    int* colsrc  = (int*)alloc((size_t)E_ * 4);
    int* ocolsrc = (int*)alloc((size_t)EO_ * 4);

    h16* h1pre = aggh;
    h16* h2pre = agg2;

    hipMemsetAsync(deg, 0, (size_t)(T_ + TO_) * 4 + 1536 * 4, stream);
    k_prep<<<8544, 256, 0, stream>>>(ei, oei, Wr1, Wn1, Wr2, Wn2, Wq, Wk, x0,
                                     deg, odeg, wt, wqkt, xh, subh);
    k_scan1m<<<528, 256, 0, stream>>>(deg, incl, bsum, odeg, oincl, obsum);
    k_scan2m<<<2, 512, 0, stream>>>(bsum, bexcl, obsum, obexcl);
    k_scan3m<<<528, 256, 0, stream>>>(incl, bexcl, rowptr, cursor, deg,
                                      oincl, obexcl, orowptr, ocursor, odeg);
    k_fillp<<<dim3(1024, 17), 256, 0, stream>>>(ei, ei + E_, cursor, colsrc,
                                                oei, oei + EO_, ocursor, ocolsrc);

    for (int i = 0; i < 3; ++i) {
        k_agg_attn<<<16512, 256, 0, stream>>>(xh, rowptr, colsrc, aggh,
            subh, wqkt + (size_t)i * 2 * 16384, bq + i * D_, bk + i * D_,
            (i == 2) ? (out + G_ * NTASK_) : nullptr, xat);
        k_aggo<<<TO_ / 8, 256, 0, stream>>>(xat, orowptr, ocolsrc, agg2);
        k_convs<<<1056, 256, 0, stream>>>(xh, aggh, xat, agg2, wt, i,
            b1 + i * D_, b2 + i * D_, h1pre, h2pre, stats + i * 512);
        k_update<<<G_ * S_, 256, 0, stream>>>(h1pre, h2pre, stats + i * 512,
            g1 + i * D_, be1 + i * D_, g2 + i * D_, be2 + i * D_, xh, subh);
    }
    k_dense<<<G_, 256, 0, stream>>>(subh, Wf1, bf1, Wf2, bf2, out);
}

// Round 5
// 679.512 us; speedup vs baseline: 3.8760x; 1.2023x over previous
//
#include <hip/hip_runtime.h>

#define G_   128
#define S_   32
#define N_   32
#define D_   128
#define T_   (G_*S_*N_)    // 131072
#define TO_  (G_*N_)       // 4096
#define E_   1048576
#define EO_  16384
#define NTASK_ 10

typedef _Float16 h16;
typedef _Float16 half8 __attribute__((ext_vector_type(8)));
typedef _Float16 half4 __attribute__((ext_vector_type(4)));
typedef float f32x16 __attribute__((ext_vector_type(16)));

// ================= merged setup: hist(E+EO) | conv-weight split prep | qk fp16 prep | x->fp16 + submean =================
__global__ __launch_bounds__(256) void k_prep(
    const int* __restrict__ ei, const int* __restrict__ oei,
    const float* __restrict__ Wr1, const float* __restrict__ Wn1,
    const float* __restrict__ Wr2, const float* __restrict__ Wn2,
    const float* __restrict__ Wq, const float* __restrict__ Wk,
    const float* __restrict__ x0,
    int* __restrict__ deg, int* __restrict__ odeg,
    h16* __restrict__ wt, h16* __restrict__ wqkt,
    h16* __restrict__ xh, h16* __restrict__ subh)
{
    __shared__ float red[8][132];
    int b = blockIdx.x, t = threadIdx.x;
    if (b < 4160) {
        int e = b * 256 + t;
        if (e < E_) atomicAdd(&deg[ei[E_ + e]], 1);
        else        atomicAdd(&odeg[oei[EO_ + (e - E_)]], 1);
    } else if (b < 4352) {
        int idx = b - 4160, mat = idx >> 4, chunk = idx & 15;
        int arr = mat / 3, layer = mat % 3;
        const float* W = (arr == 0 ? Wr1 : arr == 1 ? Wn1 : arr == 2 ? Wr2 : Wn2) + (size_t)layer * 16384;
        h16* outh = wt + (size_t)mat * 32768;
        h16* outl = outh + 16384;
        int base = chunk * 1024;
        for (int i = t; i < 1024; i += 256) {
            int id = base + i;
            int k = id >> 7, n = id & 127;
            float v = W[id];
            h16 hi = (h16)v;
            h16 lo = (h16)(v - (float)hi);
            outh[n * 128 + k] = hi;
            outl[n * 128 + k] = lo;
        }
    } else if (b < 4448) {
        int idx = b - 4352, m = idx >> 4, chunk = idx & 15;
        int layer = m >> 1, which = m & 1;
        const float* W = (which ? Wk : Wq) + (size_t)layer * 16384;
        h16* o = wqkt + (size_t)m * 16384;
        int base = chunk * 1024;
        for (int i = t; i < 1024; i += 256) {
            int id = base + i;
            int k = id >> 7, n = id & 127;
            o[n * 128 + k] = (h16)W[id];
        }
    } else {
        int gs = b - 4448;
        int cg = t & 31, rg = t >> 5;
        int c4 = cg * 4;
        float4 ssum = make_float4(0.f, 0.f, 0.f, 0.f);
        for (int n = rg; n < 32; n += 8) {
            size_t tt = (size_t)gs * 32 + n;
            float4 v = *(const float4*)&x0[tt * 128 + c4];
            half4 o; o[0] = (h16)v.x; o[1] = (h16)v.y; o[2] = (h16)v.z; o[3] = (h16)v.w;
            *(half4*)&xh[tt * 128 + c4] = o;
            ssum.x += v.x; ssum.y += v.y; ssum.z += v.z; ssum.w += v.w;
        }
        *(float4*)&red[rg][c4] = ssum;
        __syncthreads();
        if (rg == 0) {
            float4 s = make_float4(0.f, 0.f, 0.f, 0.f);
            #pragma unroll
            for (int r = 0; r < 8; ++r) {
                float4 v = *(float4*)&red[r][c4];
                s.x += v.x; s.y += v.y; s.z += v.z; s.w += v.w;
            }
            const float inv = 1.f / 32.f;
            half4 o; o[0] = (h16)(s.x*inv); o[1] = (h16)(s.y*inv); o[2] = (h16)(s.z*inv); o[3] = (h16)(s.w*inv);
            *(half4*)&subh[(size_t)gs * 128 + c4] = o;
        }
    }
}

// ================= merged scans =================
__global__ void k_scan1m(const int* __restrict__ deg, int* __restrict__ incl, int* __restrict__ bsum,
                         const int* __restrict__ odeg, int* __restrict__ oincl, int* __restrict__ obsum)
{
    __shared__ int tmp[256];
    int b = blockIdx.x;
    const int* in; int* out; int* bs; int bloc;
    if (b < 512) { in = deg;  out = incl;  bs = bsum;  bloc = b; }
    else         { in = odeg; out = oincl; bs = obsum; bloc = b - 512; }
    int i = bloc * 256 + threadIdx.x;
    tmp[threadIdx.x] = in[i];
    __syncthreads();
    for (int off = 1; off < 256; off <<= 1) {
        int v = (threadIdx.x >= off) ? tmp[threadIdx.x - off] : 0;
        __syncthreads();
        tmp[threadIdx.x] += v;
        __syncthreads();
    }
    out[i] = tmp[threadIdx.x];
    if (threadIdx.x == 255) bs[bloc] = tmp[255];
}

__global__ void k_scan2m(const int* __restrict__ bsum, int* __restrict__ bexcl,
                         const int* __restrict__ obsum, int* __restrict__ obexcl)
{
    __shared__ int tmp[512];
    int t = threadIdx.x;
    const int* arr; int* out; int nb;
    if (blockIdx.x == 0) { arr = bsum; out = bexcl; nb = 512; }
    else                 { arr = obsum; out = obexcl; nb = 16; }
    int v = (t < nb) ? arr[t] : 0;
    tmp[t] = v;
    __syncthreads();
    for (int off = 1; off < 512; off <<= 1) {
        int u = (t >= off) ? tmp[t - off] : 0;
        __syncthreads();
        tmp[t] += u;
        __syncthreads();
    }
    if (t < nb) out[t] = tmp[t] - v;
}

__global__ void k_scan3m(const int* __restrict__ incl, const int* __restrict__ bexcl,
                         int* __restrict__ rowptr, int* __restrict__ cursor, const int* __restrict__ deg,
                         const int* __restrict__ oincl, const int* __restrict__ obexcl,
                         int* __restrict__ orowptr, int* __restrict__ ocursor, const int* __restrict__ odeg)
{
    int b = blockIdx.x;
    if (b < 512) {
        int i = b * 256 + threadIdx.x;
        int e = incl[i] + bexcl[b];
        rowptr[i + 1] = e;
        cursor[i] = e - deg[i];
        if (i == 0) rowptr[0] = 0;
    } else {
        int b2 = b - 512;
        int i = b2 * 256 + threadIdx.x;
        int e = oincl[i] + obexcl[b2];
        orowptr[i + 1] = e;
        ocursor[i] = e - odeg[i];
        if (i == 0) orowptr[0] = 0;
    }
}

// ================= partitioned CSR fill: 8 passes, dst range 16384 each; pass 8 = EO =================
__global__ __launch_bounds__(256) void k_fillp(
    const int* __restrict__ src, const int* __restrict__ dst,
    int* __restrict__ cursor, int* __restrict__ colsrc,
    const int* __restrict__ osrc, const int* __restrict__ odst,
    int* __restrict__ ocursor, int* __restrict__ ocolsrc)
{
    int p = blockIdx.y;
    if (p < 8) {
        int e0 = blockIdx.x * 1024 + threadIdx.x * 4;
        int4 d4 = *(const int4*)&dst[e0];
        #pragma unroll
        for (int j = 0; j < 4; ++j) {
            int d = (&d4.x)[j];
            if ((d >> 14) == p) {
                int s = src[e0 + j];
                int pos = atomicAdd(&cursor[d], 1);
                colsrc[pos] = s;
            }
        }
    } else {
        if (blockIdx.x >= 16) return;
        int e0 = blockIdx.x * 1024 + threadIdx.x * 4;
        int4 d4 = *(const int4*)&odst[e0];
        #pragma unroll
        for (int j = 0; j < 4; ++j) {
            int d = (&d4.x)[j];
            int s = osrc[e0 + j];
            int pos = atomicAdd(&ocursor[d], 1);
            ocolsrc[pos] = s;
        }
    }
}

// ================= lean CSR aggregation, 2 feature-plane passes (grid.y) =================
// 8 lanes x half8 (16B) per node-row-half; 32 nodes / 256-thread block; no LDS, low VGPR.
__global__ __launch_bounds__(256) void k_agg2(
    const h16* __restrict__ xh, const int* __restrict__ rowptr, const int* __restrict__ colsrc,
    h16* __restrict__ agg)
{
    const int nid = blockIdx.x * 32 + (threadIdx.x >> 3);
    const int foff = blockIdx.y * 64 + (threadIdx.x & 7) * 8;
    int e0 = rowptr[nid], e1 = rowptr[nid + 1];
    float acc[8] = {0.f,0.f,0.f,0.f,0.f,0.f,0.f,0.f};
    int e = e0;
    for (; e + 4 <= e1; e += 4) {
        int s0 = colsrc[e + 0], s1 = colsrc[e + 1], s2 = colsrc[e + 2], s3 = colsrc[e + 3];
        half8 v0 = *(const half8*)&xh[(size_t)s0 * 128 + foff];
        half8 v1 = *(const half8*)&xh[(size_t)s1 * 128 + foff];
        half8 v2 = *(const half8*)&xh[(size_t)s2 * 128 + foff];
        half8 v3 = *(const half8*)&xh[(size_t)s3 * 128 + foff];
        #pragma unroll
        for (int j = 0; j < 8; ++j)
            acc[j] += ((float)v0[j] + (float)v1[j]) + ((float)v2[j] + (float)v3[j]);
    }
    for (; e < e1; ++e) {
        int s = colsrc[e];
        half8 v = *(const half8*)&xh[(size_t)s * 128 + foff];
        #pragma unroll
        for (int j = 0; j < 8; ++j) acc[j] += (float)v[j];
    }
    half8 o;
    #pragma unroll
    for (int j = 0; j < 8; ++j) o[j] = (h16)acc[j];
    *(half8*)&agg[(size_t)nid * 128 + foff] = o;
}

// ================= per-graph attention: q/k MFMA -> softmax -> head-mean -> x_atten =================
__global__ __launch_bounds__(256) void k_attn(
    const h16* __restrict__ subh, const h16* __restrict__ wqkt_l,
    const float* __restrict__ bql, const float* __restrict__ bkl,
    const h16* __restrict__ xh, float* __restrict__ heat, h16* __restrict__ xat)
{
    __shared__ __align__(16) char smem[25600];
    const int tid = threadIdx.x;
    const int g = blockIdx.x;
    h16* aF = (h16*)smem;                   // 512 frag units x 8 h16 = 8KB (sub in MFMA A-frag order)
    h16* qkT = (h16*)(smem + 8192);         // [mat][n(128)][34] fp16 (channel-major q/k)
    float* attn_s = (float*)smem;           // alias over aF after GEMM phase
    #pragma unroll
    for (int it = 0; it < 2; ++it) {
        int u = tid + it * 256;
        int kq = u >> 6, l = u & 63;
        int m = l & 31, ko = kq * 16 + (l >> 5) * 8;
        *(half8*)&aF[u * 8] = *(const half8*)&subh[((size_t)g * 32 + m) * 128 + ko];
    }
    __syncthreads();
    const int w = tid >> 6, lane = tid & 63, lm = lane & 31, lh = lane >> 5;
    const int mat = w & 1, ntp = (w >> 1) * 2;
    const h16* Wt = wqkt_l + (size_t)mat * 16384;
    const float* bias = mat ? bkl : bql;
    f32x16 a0, a1;
    #pragma unroll
    for (int r = 0; r < 16; ++r) { a0[r] = 0.f; a1[r] = 0.f; }
    #pragma unroll
    for (int kq = 0; kq < 8; ++kq) {
        half8 av = *(half8*)&aF[(kq * 64 + lane) * 8];
        half8 b0 = *(const half8*)&Wt[(size_t)(ntp * 32 + lm) * 128 + kq * 16 + lh * 8];
        half8 b1 = *(const half8*)&Wt[(size_t)((ntp + 1) * 32 + lm) * 128 + kq * 16 + lh * 8];
        a0 = __builtin_amdgcn_mfma_f32_32x32x16_f16(av, b0, a0, 0, 0, 0);
        a1 = __builtin_amdgcn_mfma_f32_32x32x16_f16(av, b1, a1, 0, 0, 0);
    }
    __syncthreads();
    #pragma unroll
    for (int ti = 0; ti < 2; ++ti) {
        int n = (ntp + ti) * 32 + lm;
        float bn = bias[n];
        #pragma unroll
        for (int r = 0; r < 16; ++r) {
            int s = (r & 3) + 8 * (r >> 2) + 4 * lh;
            float v = (ti ? a1[r] : a0[r]) + bn;
            qkT[(mat * 128 + n) * 34 + s] = (h16)v;
        }
    }
    for (int i = tid; i < 1024; i += 256) attn_s[i] = 0.f;
    __syncthreads();
    if (tid < 128) {
        int h = tid >> 5, i = tid & 31;
        float qreg[32];
        #pragma unroll
        for (int d = 0; d < 32; ++d) qreg[d] = (float)qkT[(h * 32 + d) * 34 + i];
        float sc[32];
        const float scale = 0.17677669529663687f; // 1/sqrt(32)
        float mx = -1e30f;
        #pragma unroll
        for (int j = 0; j < 32; ++j) {
            float d = 0.f;
            #pragma unroll
            for (int d0 = 0; d0 < 32; ++d0) d += qreg[d0] * (float)qkT[(128 + h * 32 + d0) * 34 + j];
            d *= scale;
            sc[j] = d;
            mx = fmaxf(mx, d);
        }
        float ssum = 0.f;
        #pragma unroll
        for (int j = 0; j < 32; ++j) { float ee = __expf(sc[j] - mx); sc[j] = ee; ssum += ee; }
        float inv = 0.25f / ssum;  // head-mean folded in
        #pragma unroll
        for (int j = 0; j < 32; ++j) atomicAdd(&attn_s[i * 32 + j], sc[j] * inv);
    }
    __syncthreads();
    if (heat != nullptr && g == 127) {
        for (int idx = tid; idx < 1024; idx += 256) heat[idx] = attn_s[idx];
    }
    {
        int c4 = (tid & 31) * 4;
        int ng = tid >> 5;
        for (int n = ng; n < 32; n += 8) {
            float ax = 0.f, ay = 0.f, az = 0.f, aw = 0.f;
            #pragma unroll
            for (int s = 0; s < 32; ++s) {
                float a = attn_s[s * 32 + n];
                half4 xv = *(const half4*)&xh[(((size_t)g * 32 + s) * 32 + n) * 128 + c4];
                ax += a * (float)xv[0]; ay += a * (float)xv[1];
                az += a * (float)xv[2]; aw += a * (float)xv[3];
            }
            half4 o; o[0] = (h16)ax; o[1] = (h16)ay; o[2] = (h16)az; o[3] = (h16)aw;
            *(half4*)&xat[((size_t)g * 32 + n) * 128 + c4] = o;
        }
    }
}

// ================= CSR aggregation for original graph (small, L2-resident) =================
__global__ __launch_bounds__(256) void k_aggo(
    const h16* __restrict__ x, const int* __restrict__ rowptr, const int* __restrict__ colsrc,
    h16* __restrict__ agg)
{
    int nid = blockIdx.x * 8 + (threadIdx.x >> 5);
    int lane = threadIdx.x & 31;
    int e0 = rowptr[nid], e1 = rowptr[nid + 1];
    float ax = 0.f, ay = 0.f, az = 0.f, aw = 0.f;
    int e = e0;
    for (; e + 4 <= e1; e += 4) {
        int s0 = colsrc[e + 0], s1 = colsrc[e + 1], s2 = colsrc[e + 2], s3 = colsrc[e + 3];
        half4 v0 = *(const half4*)&x[(size_t)s0 * 128 + lane * 4];
        half4 v1 = *(const half4*)&x[(size_t)s1 * 128 + lane * 4];
        half4 v2 = *(const half4*)&x[(size_t)s2 * 128 + lane * 4];
        half4 v3 = *(const half4*)&x[(size_t)s3 * 128 + lane * 4];
        ax += ((float)v0[0] + (float)v1[0]) + ((float)v2[0] + (float)v3[0]);
        ay += ((float)v0[1] + (float)v1[1]) + ((float)v2[1] + (float)v3[1]);
        az += ((float)v0[2] + (float)v1[2]) + ((float)v2[2] + (float)v3[2]);
        aw += ((float)v0[3] + (float)v1[3]) + ((float)v2[3] + (float)v3[3]);
    }
    for (; e < e1; ++e) {
        int s = colsrc[e];
        half4 v = *(const half4*)&x[(size_t)s * 128 + lane * 4];
        ax += (float)v[0]; ay += (float)v[1]; az += (float)v[2]; aw += (float)v[3];
    }
    half4 o; o[0] = (h16)ax; o[1] = (h16)ay; o[2] = (h16)az; o[3] = (h16)aw;
    *(half4*)&agg[(size_t)nid * 128 + lane * 4] = o;
}

// ================= merged MFMA GraphConv (T branch | TO branch) + BN stats =================
__global__ __launch_bounds__(256) void k_convs(
    const h16* __restrict__ xT, const h16* __restrict__ aggT,
    const h16* __restrict__ xO, const h16* __restrict__ aggO,
    const h16* __restrict__ wt, int layer,
    const float* __restrict__ b1l, const float* __restrict__ b2l,
    h16* __restrict__ h1, h16* __restrict__ h2, float* __restrict__ stats)
{
    __shared__ h16 lsA[4096];
    __shared__ h16 lsBh[4096];
    __shared__ h16 lsBl[4096];
    __shared__ float csum[128], csq[128];
    const int tid = threadIdx.x;
    const h16 *A0, *A1, *W0, *W1; const float* bias; h16* outp; float *gsum, *gsq; size_t row0;
    if (blockIdx.x < 1024) {
        A0 = xT; A1 = aggT;
        W0 = wt + (size_t)(0 * 3 + layer) * 32768;
        W1 = wt + (size_t)(1 * 3 + layer) * 32768;
        bias = b1l; outp = h1; gsum = stats; gsq = stats + 128;
        row0 = (size_t)blockIdx.x * 128;
    } else {
        A0 = xO; A1 = aggO;
        W0 = wt + (size_t)(2 * 3 + layer) * 32768;
        W1 = wt + (size_t)(3 * 3 + layer) * 32768;
        bias = b2l; outp = h2; gsum = stats + 256; gsq = stats + 384;
        row0 = (size_t)(blockIdx.x - 1024) * 128;
    }
    if (tid < 128) { csum[tid] = 0.f; csq[tid] = 0.f; }
    const int w = tid >> 6, lane = tid & 63, lm = lane & 31, lh = lane >> 5;
    const int mbase = (w & 1) * 64, nbase = (w >> 1) * 64;
    f32x16 acc[2][2];
    #pragma unroll
    for (int mi = 0; mi < 2; ++mi)
        #pragma unroll
        for (int ni = 0; ni < 2; ++ni)
            #pragma unroll
            for (int r = 0; r < 16; ++r) acc[mi][ni][r] = 0.f;

    for (int p = 0; p < 2; ++p) {
        const h16* A  = p ? A1 : A0;
        const h16* Bh = p ? W1 : W0;
        const h16* Bl = Bh + 16384;
        for (int kc = 0; kc < 4; ++kc) {
            __syncthreads();
            #pragma unroll
            for (int it = 0; it < 2; ++it) {
                int u = tid + it * 256;
                int m = u & 127, ch = u >> 7;
                *(half8*)&lsA[u * 8]  = *(const half8*)&A[(row0 + m) * 128 + kc * 32 + ch * 8];
                *(half8*)&lsBh[u * 8] = *(const half8*)&Bh[(size_t)m * 128 + kc * 32 + ch * 8];
                *(half8*)&lsBl[u * 8] = *(const half8*)&Bl[(size_t)m * 128 + kc * 32 + ch * 8];
            }
            __syncthreads();
            #pragma unroll
            for (int c = 0; c < 2; ++c) {
                const int base = (2 * c + lh) * 128;
                half8 a0  = *(half8*)&lsA[(base + mbase + lm) * 8];
                half8 a1  = *(half8*)&lsA[(base + mbase + 32 + lm) * 8];
                half8 bh0 = *(half8*)&lsBh[(base + nbase + lm) * 8];
                half8 bh1 = *(half8*)&lsBh[(base + nbase + 32 + lm) * 8];
                half8 bl0 = *(half8*)&lsBl[(base + nbase + lm) * 8];
                half8 bl1 = *(half8*)&lsBl[(base + nbase + 32 + lm) * 8];
                acc[0][0] = __builtin_amdgcn_mfma_f32_32x32x16_f16(a0, bh0, acc[0][0], 0, 0, 0);
                acc[0][0] = __builtin_amdgcn_mfma_f32_32x32x16_f16(a0, bl0, acc[0][0], 0, 0, 0);
                acc[0][1] = __builtin_amdgcn_mfma_f32_32x32x16_f16(a0, bh1, acc[0][1], 0, 0, 0);
                acc[0][1] = __builtin_amdgcn_mfma_f32_32x32x16_f16(a0, bl1, acc[0][1], 0, 0, 0);
                acc[1][0] = __builtin_amdgcn_mfma_f32_32x32x16_f16(a1, bh0, acc[1][0], 0, 0, 0);
                acc[1][0] = __builtin_amdgcn_mfma_f32_32x32x16_f16(a1, bl0, acc[1][0], 0, 0, 0);
                acc[1][1] = __builtin_amdgcn_mfma_f32_32x32x16_f16(a1, bh1, acc[1][1], 0, 0, 0);
                acc[1][1] = __builtin_amdgcn_mfma_f32_32x32x16_f16(a1, bl1, acc[1][1], 0, 0, 0);
            }
        }
    }
    #pragma unroll
    for (int ni = 0; ni < 2; ++ni) {
        int col = nbase + ni * 32 + lm;
        float bcol = bias[col];
        float s = 0.f, q = 0.f;
        #pragma unroll
        for (int mi = 0; mi < 2; ++mi) {
            #pragma unroll
            for (int r = 0; r < 16; ++r) {
                int row = mbase + mi * 32 + (r & 3) + 8 * (r >> 2) + 4 * lh;
                float o = acc[mi][ni][r] + bcol;
                outp[(row0 + row) * 128 + col] = (h16)o;
                s += o; q += o * o;
            }
        }
        atomicAdd(&csum[col], s);
        atomicAdd(&csq[col], q);
    }
    __syncthreads();
    if (tid < 128) atomicAdd(&gsum[tid], csum[tid]);
    else           atomicAdd(&gsq[tid - 128], csq[tid - 128]);
}

// ================= x = relu(BN1(h1)+BN2(h2)); fused BN-finalize + next submean =================
__global__ __launch_bounds__(256) void k_update(
    const h16* __restrict__ hpre, const h16* __restrict__ h2pre,
    const float* __restrict__ stats,
    const float* __restrict__ g1, const float* __restrict__ be1,
    const float* __restrict__ g2, const float* __restrict__ be2,
    h16* __restrict__ x, h16* __restrict__ subh)
{
    __shared__ float sA[128], hA[128], sB[128], hB[128];
    __shared__ float red[8][132];
    int gs = blockIdx.x, g = gs >> 5, tid = threadIdx.x;
    if (tid < 128) {
        float mu = stats[tid] * (1.f / T_);
        float var = stats[128 + tid] * (1.f / T_) - mu * mu;
        float sc = g1[tid] * rsqrtf(var + 1e-5f);
        sA[tid] = sc; hA[tid] = be1[tid] - mu * sc;
    } else {
        int c = tid - 128;
        float mu = stats[256 + c] * (1.f / TO_);
        float var = stats[384 + c] * (1.f / TO_) - mu * mu;
        float sc = g2[c] * rsqrtf(var + 1e-5f);
        sB[c] = sc; hB[c] = be2[c] - mu * sc;
    }
    __syncthreads();
    int cg = tid & 31, ng = tid >> 5;
    int c4 = cg * 4;
    float4 ssum = make_float4(0.f, 0.f, 0.f, 0.f);
    for (int n = ng; n < 32; n += 8) {
        size_t t = (size_t)gs * 32 + n;
        half4 h1v = *(const half4*)&hpre[t * 128 + c4];
        half4 h2v = *(const half4*)&h2pre[((size_t)g * 32 + n) * 128 + c4];
        float o0 = fmaxf((float)h1v[0] * sA[c4+0] + hA[c4+0] + (float)h2v[0] * sB[c4+0] + hB[c4+0], 0.f);
        float o1 = fmaxf((float)h1v[1] * sA[c4+1] + hA[c4+1] + (float)h2v[1] * sB[c4+1] + hB[c4+1], 0.f);
        float o2 = fmaxf((float)h1v[2] * sA[c4+2] + hA[c4+2] + (float)h2v[2] * sB[c4+2] + hB[c4+2], 0.f);
        float o3 = fmaxf((float)h1v[3] * sA[c4+3] + hA[c4+3] + (float)h2v[3] * sB[c4+3] + hB[c4+3], 0.f);
        half4 o; o[0] = (h16)o0; o[1] = (h16)o1; o[2] = (h16)o2; o[3] = (h16)o3;
        *(half4*)&x[t * 128 + c4] = o;
        ssum.x += o0; ssum.y += o1; ssum.z += o2; ssum.w += o3;
    }
    *(float4*)&red[ng][c4] = ssum;
    __syncthreads();
    if (ng == 0) {
        float4 s = make_float4(0.f, 0.f, 0.f, 0.f);
        #pragma unroll
        for (int r = 0; r < 8; ++r) {
            float4 v = *(float4*)&red[r][c4];
            s.x += v.x; s.y += v.y; s.z += v.z; s.w += v.w;
        }
        const float inv = 1.f / 32.f;
        half4 o; o[0] = (h16)(s.x*inv); o[1] = (h16)(s.y*inv); o[2] = (h16)(s.z*inv); o[3] = (h16)(s.w*inv);
        *(half4*)&subh[(size_t)gs * 128 + c4] = o;
    }
}

// ================= final head =================
__global__ __launch_bounds__(256) void k_dense(const h16* __restrict__ subh, const float* __restrict__ Wf1,
    const float* __restrict__ bf1, const float* __restrict__ Wf2, const float* __restrict__ bf2,
    float* __restrict__ out)
{
    int g = blockIdx.x, tid = threadIdx.x;
    __shared__ float hgs[128];
    __shared__ float hid[256];
    if (tid < 128) {
        float s = 0.f;
        for (int ss = 0; ss < 32; ++ss) s += (float)subh[((size_t)g * 32 + ss) * 128 + tid];
        hgs[tid] = s * (1.f / 32.f);
    }
    __syncthreads();
    float a = bf1[tid];
    for (int k = 0; k < 128; ++k) a += hgs[k] * Wf1[k * 256 + tid];
    hid[tid] = fmaxf(a, 0.f);
    __syncthreads();
    if (tid < 10) {
        float o = bf2[tid];
        for (int k = 0; k < 256; ++k) o += hid[k] * Wf2[k * 10 + tid];
        out[g * 10 + tid] = o;
    }
}

extern "C" void kernel_launch(void* const* d_in, const int* in_sizes, int n_in,
                              void* d_out, int out_size, void* d_ws, size_t ws_size,
                              hipStream_t stream)
{
    (void)in_sizes; (void)n_in; (void)out_size; (void)ws_size;
    const float* x0  = (const float*)d_in[0];
    const int*   ei  = (const int*)d_in[1];
    const int*   oei = (const int*)d_in[2];
    const float* Wr1 = (const float*)d_in[3];
    const float* Wn1 = (const float*)d_in[4];
    const float* b1  = (const float*)d_in[5];
    const float* g1  = (const float*)d_in[6];
    const float* be1 = (const float*)d_in[7];
    const float* Wr2 = (const float*)d_in[8];
    const float* Wn2 = (const float*)d_in[9];
    const float* b2  = (const float*)d_in[10];
    const float* g2  = (const float*)d_in[11];
    const float* be2 = (const float*)d_in[12];
    const float* Wq  = (const float*)d_in[13];
    const float* bq  = (const float*)d_in[14];
    const float* Wk  = (const float*)d_in[15];
    const float* bk  = (const float*)d_in[16];
    const float* Wf1 = (const float*)d_in[17];
    const float* bf1 = (const float*)d_in[18];
    const float* Wf2 = (const float*)d_in[19];
    const float* bf2 = (const float*)d_in[20];
    float* out = (float*)d_out;

    char* w = (char*)d_ws;
    size_t off = 0;
    auto alloc = [&](size_t bytes) { void* p = w + off; off = (off + bytes + 255) & ~(size_t)255; return p; };
    h16* xh     = (h16*)alloc((size_t)T_ * D_ * 2);
    h16* aggh   = (h16*)alloc((size_t)T_ * D_ * 2);   // aliased as h1pre (block-local RAW safe)
    h16* agg2   = (h16*)alloc((size_t)TO_ * D_ * 2);  // aliased as h2pre
    h16* xat    = (h16*)alloc((size_t)TO_ * D_ * 2);
    h16* wt     = (h16*)alloc((size_t)12 * 32768 * 2);
    h16* wqkt   = (h16*)alloc((size_t)6 * 16384 * 2);
    h16* subh   = (h16*)alloc((size_t)G_ * S_ * D_ * 2);
    int* deg     = (int*)alloc((size_t)(T_ + TO_) * 4 + 1536 * 4);
    int* odeg    = deg + T_;
    float* stats = (float*)(deg + T_ + TO_);
    int* incl    = (int*)alloc((size_t)(T_ + TO_) * 4);
    int* oincl   = incl + T_;
    int* bsum    = (int*)alloc(512 * 4);
    int* obsum   = (int*)alloc(16 * 4);
    int* bexcl   = (int*)alloc(512 * 4);
    int* obexcl  = (int*)alloc(16 * 4);
    int* rowptr  = (int*)alloc((T_ + 1) * 4);
    int* orowptr = (int*)alloc((TO_ + 1) * 4);
    int* cursor  = (int*)alloc(T_ * 4);
    int* ocursor = (int*)alloc(TO_ * 4);
    int* colsrc  = (int*)alloc((size_t)E_ * 4);
    int* ocolsrc = (int*)alloc((size_t)EO_ * 4);

    h16* h1pre = aggh;
    h16* h2pre = agg2;

    hipMemsetAsync(deg, 0, (size_t)(T_ + TO_) * 4 + 1536 * 4, stream);
    k_prep<<<8544, 256, 0, stream>>>(ei, oei, Wr1, Wn1, Wr2, Wn2, Wq, Wk, x0,
                                     deg, odeg, wt, wqkt, xh, subh);
    k_scan1m<<<528, 256, 0, stream>>>(deg, incl, bsum, odeg, oincl, obsum);
    k_scan2m<<<2, 512, 0, stream>>>(bsum, bexcl, obsum, obexcl);
    k_scan3m<<<528, 256, 0, stream>>>(incl, bexcl, rowptr, cursor, deg,
                                      oincl, obexcl, orowptr, ocursor, odeg);
    k_fillp<<<dim3(1024, 9), 256, 0, stream>>>(ei, ei + E_, cursor, colsrc,
                                               oei, oei + EO_, ocursor, ocolsrc);

    for (int i = 0; i < 3; ++i) {
        k_agg2<<<dim3(T_ / 32, 2), 256, 0, stream>>>(xh, rowptr, colsrc, aggh);
        k_attn<<<G_, 256, 0, stream>>>(subh, wqkt + (size_t)i * 2 * 16384,
            bq + i * D_, bk + i * D_, xh,
            (i == 2) ? (out + G_ * NTASK_) : nullptr, xat);
        k_aggo<<<TO_ / 8, 256, 0, stream>>>(xat, orowptr, ocolsrc, agg2);
        k_convs<<<1056, 256, 0, stream>>>(xh, aggh, xat, agg2, wt, i,
            b1 + i * D_, b2 + i * D_, h1pre, h2pre, stats + i * 512);
        k_update<<<G_ * S_, 256, 0, stream>>>(h1pre, h2pre, stats + i * 512,
            g1 + i * D_, be1 + i * D_, g2 + i * D_, be2 + i * D_, xh, subh);
    }
    k_dense<<<G_, 256, 0, stream>>>(subh, Wf1, bf1, Wf2, bf2, out);
}

// Round 6
// 656.364 us; speedup vs baseline: 4.0127x; 1.0353x over previous
//
#include <hip/hip_runtime.h>

#define G_   128
#define S_   32
#define N_   32
#define D_   128
#define T_   (G_*S_*N_)    // 131072
#define TO_  (G_*N_)       // 4096
#define E_   1048576
#define EO_  16384
#define NTASK_ 10
#define CAP_ 32            // bucket capacity per node (Poisson(7.6): P(deg>32) ~ 1e-11)

typedef _Float16 h16;
typedef _Float16 half8 __attribute__((ext_vector_type(8)));
typedef _Float16 half4 __attribute__((ext_vector_type(4)));
typedef float f32x16 __attribute__((ext_vector_type(16)));

// ================= merged setup =================
// grid: [0,8192)        bucketed fill of T edges, dst-partition p = b>>10 (8 passes x 1024 blocks)
//       [8192,8208)     bucketed fill of EO edges (16 blocks)
//       [8208,8400)     conv-weight split-fp16 transpose prep (12 mats x 16 chunks)
//       [8400,8496)     q/k fp16 transpose prep (6 x 16)
//       [8496,12592)    x0 -> fp16 + initial subgraph mean (4096 blocks)
__global__ __launch_bounds__(256) void k_prep(
    const int* __restrict__ ei, const int* __restrict__ oei,
    const float* __restrict__ Wr1, const float* __restrict__ Wn1,
    const float* __restrict__ Wr2, const float* __restrict__ Wn2,
    const float* __restrict__ Wq, const float* __restrict__ Wk,
    const float* __restrict__ x0,
    int* __restrict__ cnt, int* __restrict__ ocnt,
    int* __restrict__ colsrc, int* __restrict__ ocolsrc,
    h16* __restrict__ wt, h16* __restrict__ wqkt,
    h16* __restrict__ xh, h16* __restrict__ subh)
{
    __shared__ float red[8][132];
    int b = blockIdx.x, t = threadIdx.x;
    if (b < 8192) {
        const int p = b >> 10;
        const int e0 = (b & 1023) * 1024 + t * 4;
        const int4 d4 = *(const int4*)&ei[E_ + e0];
        const int4 s4 = *(const int4*)&ei[e0];
        #pragma unroll
        for (int j = 0; j < 4; ++j) {
            int d = (&d4.x)[j];
            if ((d >> 14) == p) {
                int pos = atomicAdd(&cnt[d], 1);
                if (pos < CAP_) colsrc[(d << 5) + pos] = (&s4.x)[j];
            }
        }
    } else if (b < 8208) {
        const int e0 = (b - 8192) * 1024 + t * 4;
        const int4 d4 = *(const int4*)&oei[EO_ + e0];
        const int4 s4 = *(const int4*)&oei[e0];
        #pragma unroll
        for (int j = 0; j < 4; ++j) {
            int d = (&d4.x)[j];
            int pos = atomicAdd(&ocnt[d], 1);
            if (pos < CAP_) ocolsrc[(d << 5) + pos] = (&s4.x)[j];
        }
    } else if (b < 8400) {
        int idx = b - 8208, mat = idx >> 4, chunk = idx & 15;
        int arr = mat / 3, layer = mat % 3;
        const float* W = (arr == 0 ? Wr1 : arr == 1 ? Wn1 : arr == 2 ? Wr2 : Wn2) + (size_t)layer * 16384;
        h16* outh = wt + (size_t)mat * 32768;
        h16* outl = outh + 16384;
        int base = chunk * 1024;
        for (int i = t; i < 1024; i += 256) {
            int id = base + i;
            int k = id >> 7, n = id & 127;
            float v = W[id];
            h16 hi = (h16)v;
            h16 lo = (h16)(v - (float)hi);
            outh[n * 128 + k] = hi;
            outl[n * 128 + k] = lo;
        }
    } else if (b < 8496) {
        int idx = b - 8400, m = idx >> 4, chunk = idx & 15;
        int layer = m >> 1, which = m & 1;
        const float* W = (which ? Wk : Wq) + (size_t)layer * 16384;
        h16* o = wqkt + (size_t)m * 16384;
        int base = chunk * 1024;
        for (int i = t; i < 1024; i += 256) {
            int id = base + i;
            int k = id >> 7, n = id & 127;
            o[n * 128 + k] = (h16)W[id];
        }
    } else {
        int gs = b - 8496;
        int cg = t & 31, rg = t >> 5;
        int c4 = cg * 4;
        float4 ssum = make_float4(0.f, 0.f, 0.f, 0.f);
        for (int n = rg; n < 32; n += 8) {
            size_t tt = (size_t)gs * 32 + n;
            float4 v = *(const float4*)&x0[tt * 128 + c4];
            half4 o; o[0] = (h16)v.x; o[1] = (h16)v.y; o[2] = (h16)v.z; o[3] = (h16)v.w;
            *(half4*)&xh[tt * 128 + c4] = o;
            ssum.x += v.x; ssum.y += v.y; ssum.z += v.z; ssum.w += v.w;
        }
        *(float4*)&red[rg][c4] = ssum;
        __syncthreads();
        if (rg == 0) {
            float4 s = make_float4(0.f, 0.f, 0.f, 0.f);
            #pragma unroll
            for (int r = 0; r < 8; ++r) {
                float4 v = *(float4*)&red[r][c4];
                s.x += v.x; s.y += v.y; s.z += v.z; s.w += v.w;
            }
            const float inv = 1.f / 32.f;
            half4 o; o[0] = (h16)(s.x*inv); o[1] = (h16)(s.y*inv); o[2] = (h16)(s.z*inv); o[3] = (h16)(s.w*inv);
            *(half4*)&subh[(size_t)gs * 128 + c4] = o;
        }
    }
}

// ================= bucketed CSR aggregation, 2 feature-plane passes (grid.y) =================
// 8 lanes x half8 (16B) per node-row-half; 32 nodes / 256-thread block; int4 edge loads.
__global__ __launch_bounds__(256) void k_agg2(
    const h16* __restrict__ xh, const int* __restrict__ cnt, const int* __restrict__ colsrc,
    h16* __restrict__ agg)
{
    const int nid = blockIdx.x * 32 + (threadIdx.x >> 3);
    const int foff = blockIdx.y * 64 + (threadIdx.x & 7) * 8;
    int n = cnt[nid]; n = (n > CAP_) ? CAP_ : n;
    const int* __restrict__ bucket = colsrc + ((size_t)nid << 5);
    float acc[8] = {0.f,0.f,0.f,0.f,0.f,0.f,0.f,0.f};
    for (int e = 0; e < n; e += 4) {
        int4 s4 = *(const int4*)&bucket[e];
        #pragma unroll
        for (int j = 0; j < 4; ++j) {
            bool ok = (e + j) < n;
            int s = ok ? (&s4.x)[j] : 0;
            half8 v = *(const half8*)&xh[(size_t)s * 128 + foff];
            if (ok) {
                #pragma unroll
                for (int q = 0; q < 8; ++q) acc[q] += (float)v[q];
            }
        }
    }
    half8 o;
    #pragma unroll
    for (int j = 0; j < 8; ++j) o[j] = (h16)acc[j];
    *(half8*)&agg[(size_t)nid * 128 + foff] = o;
}

// ================= per-graph attention: q/k MFMA -> softmax -> head-mean -> x_atten =================
__global__ __launch_bounds__(256) void k_attn(
    const h16* __restrict__ subh, const h16* __restrict__ wqkt_l,
    const float* __restrict__ bql, const float* __restrict__ bkl,
    const h16* __restrict__ xh, float* __restrict__ heat, h16* __restrict__ xat)
{
    __shared__ __align__(16) char smem[25600];
    const int tid = threadIdx.x;
    const int g = blockIdx.x;
    h16* aF = (h16*)smem;                   // 512 frag units x 8 h16 = 8KB
    h16* qkT = (h16*)(smem + 8192);         // [mat][n(128)][34] fp16
    float* attn_s = (float*)smem;           // alias over aF after GEMM phase
    #pragma unroll
    for (int it = 0; it < 2; ++it) {
        int u = tid + it * 256;
        int kq = u >> 6, l = u & 63;
        int m = l & 31, ko = kq * 16 + (l >> 5) * 8;
        *(half8*)&aF[u * 8] = *(const half8*)&subh[((size_t)g * 32 + m) * 128 + ko];
    }
    __syncthreads();
    const int w = tid >> 6, lane = tid & 63, lm = lane & 31, lh = lane >> 5;
    const int mat = w & 1, ntp = (w >> 1) * 2;
    const h16* Wt = wqkt_l + (size_t)mat * 16384;
    const float* bias = mat ? bkl : bql;
    f32x16 a0, a1;
    #pragma unroll
    for (int r = 0; r < 16; ++r) { a0[r] = 0.f; a1[r] = 0.f; }
    #pragma unroll
    for (int kq = 0; kq < 8; ++kq) {
        half8 av = *(half8*)&aF[(kq * 64 + lane) * 8];
        half8 b0 = *(const half8*)&Wt[(size_t)(ntp * 32 + lm) * 128 + kq * 16 + lh * 8];
        half8 b1 = *(const half8*)&Wt[(size_t)((ntp + 1) * 32 + lm) * 128 + kq * 16 + lh * 8];
        a0 = __builtin_amdgcn_mfma_f32_32x32x16_f16(av, b0, a0, 0, 0, 0);
        a1 = __builtin_amdgcn_mfma_f32_32x32x16_f16(av, b1, a1, 0, 0, 0);
    }
    __syncthreads();
    #pragma unroll
    for (int ti = 0; ti < 2; ++ti) {
        int n = (ntp + ti) * 32 + lm;
        float bn = bias[n];
        #pragma unroll
        for (int r = 0; r < 16; ++r) {
            int s = (r & 3) + 8 * (r >> 2) + 4 * lh;
            float v = (ti ? a1[r] : a0[r]) + bn;
            qkT[(mat * 128 + n) * 34 + s] = (h16)v;
        }
    }
    for (int i = tid; i < 1024; i += 256) attn_s[i] = 0.f;
    __syncthreads();
    if (tid < 128) {
        int h = tid >> 5, i = tid & 31;
        float qreg[32];
        #pragma unroll
        for (int d = 0; d < 32; ++d) qreg[d] = (float)qkT[(h * 32 + d) * 34 + i];
        float sc[32];
        const float scale = 0.17677669529663687f; // 1/sqrt(32)
        float mx = -1e30f;
        #pragma unroll
        for (int j = 0; j < 32; ++j) {
            float d = 0.f;
            #pragma unroll
            for (int d0 = 0; d0 < 32; ++d0) d += qreg[d0] * (float)qkT[(128 + h * 32 + d0) * 34 + j];
            d *= scale;
            sc[j] = d;
            mx = fmaxf(mx, d);
        }
        float ssum = 0.f;
        #pragma unroll
        for (int j = 0; j < 32; ++j) { float ee = __expf(sc[j] - mx); sc[j] = ee; ssum += ee; }
        float inv = 0.25f / ssum;  // head-mean folded in
        #pragma unroll
        for (int j = 0; j < 32; ++j) atomicAdd(&attn_s[i * 32 + j], sc[j] * inv);
    }
    __syncthreads();
    if (heat != nullptr && g == 127) {
        for (int idx = tid; idx < 1024; idx += 256) heat[idx] = attn_s[idx];
    }
    {
        int c4 = (tid & 31) * 4;
        int ng = tid >> 5;
        for (int n = ng; n < 32; n += 8) {
            float ax = 0.f, ay = 0.f, az = 0.f, aw = 0.f;
            #pragma unroll
            for (int s = 0; s < 32; ++s) {
                float a = attn_s[s * 32 + n];
                half4 xv = *(const half4*)&xh[(((size_t)g * 32 + s) * 32 + n) * 128 + c4];
                ax += a * (float)xv[0]; ay += a * (float)xv[1];
                az += a * (float)xv[2]; aw += a * (float)xv[3];
            }
            half4 o; o[0] = (h16)ax; o[1] = (h16)ay; o[2] = (h16)az; o[3] = (h16)aw;
            *(half4*)&xat[((size_t)g * 32 + n) * 128 + c4] = o;
        }
    }
}

// ================= bucketed aggregation for original graph (small, L2-resident) =================
__global__ __launch_bounds__(256) void k_aggo(
    const h16* __restrict__ x, const int* __restrict__ ocnt, const int* __restrict__ ocolsrc,
    h16* __restrict__ agg)
{
    int nid = blockIdx.x * 8 + (threadIdx.x >> 5);
    int lane = threadIdx.x & 31;
    int n = ocnt[nid]; n = (n > CAP_) ? CAP_ : n;
    const int* __restrict__ bucket = ocolsrc + ((size_t)nid << 5);
    float ax = 0.f, ay = 0.f, az = 0.f, aw = 0.f;
    for (int e = 0; e < n; e += 4) {
        int4 s4 = *(const int4*)&bucket[e];
        #pragma unroll
        for (int j = 0; j < 4; ++j) {
            bool ok = (e + j) < n;
            int s = ok ? (&s4.x)[j] : 0;
            half4 v = *(const half4*)&x[(size_t)s * 128 + lane * 4];
            if (ok) { ax += (float)v[0]; ay += (float)v[1]; az += (float)v[2]; aw += (float)v[3]; }
        }
    }
    half4 o; o[0] = (h16)ax; o[1] = (h16)ay; o[2] = (h16)az; o[3] = (h16)aw;
    *(half4*)&agg[(size_t)nid * 128 + lane * 4] = o;
}

// ================= merged MFMA GraphConv (T branch | TO branch) + BN stats =================
__global__ __launch_bounds__(256) void k_convs(
    const h16* __restrict__ xT, const h16* __restrict__ aggT,
    const h16* __restrict__ xO, const h16* __restrict__ aggO,
    const h16* __restrict__ wt, int layer,
    const float* __restrict__ b1l, const float* __restrict__ b2l,
    h16* __restrict__ h1, h16* __restrict__ h2, float* __restrict__ stats)
{
    __shared__ h16 lsA[4096];
    __shared__ h16 lsBh[4096];
    __shared__ h16 lsBl[4096];
    __shared__ float csum[128], csq[128];
    const int tid = threadIdx.x;
    const h16 *A0, *A1, *W0, *W1; const float* bias; h16* outp; float *gsum, *gsq; size_t row0;
    if (blockIdx.x < 1024) {
        A0 = xT; A1 = aggT;
        W0 = wt + (size_t)(0 * 3 + layer) * 32768;
        W1 = wt + (size_t)(1 * 3 + layer) * 32768;
        bias = b1l; outp = h1; gsum = stats; gsq = stats + 128;
        row0 = (size_t)blockIdx.x * 128;
    } else {
        A0 = xO; A1 = aggO;
        W0 = wt + (size_t)(2 * 3 + layer) * 32768;
        W1 = wt + (size_t)(3 * 3 + layer) * 32768;
        bias = b2l; outp = h2; gsum = stats + 256; gsq = stats + 384;
        row0 = (size_t)(blockIdx.x - 1024) * 128;
    }
    if (tid < 128) { csum[tid] = 0.f; csq[tid] = 0.f; }
    const int w = tid >> 6, lane = tid & 63, lm = lane & 31, lh = lane >> 5;
    const int mbase = (w & 1) * 64, nbase = (w >> 1) * 64;
    f32x16 acc[2][2];
    #pragma unroll
    for (int mi = 0; mi < 2; ++mi)
        #pragma unroll
        for (int ni = 0; ni < 2; ++ni)
            #pragma unroll
            for (int r = 0; r < 16; ++r) acc[mi][ni][r] = 0.f;

    for (int p = 0; p < 2; ++p) {
        const h16* A  = p ? A1 : A0;
        const h16* Bh = p ? W1 : W0;
        const h16* Bl = Bh + 16384;
        for (int kc = 0; kc < 4; ++kc) {
            __syncthreads();
            #pragma unroll
            for (int it = 0; it < 2; ++it) {
                int u = tid + it * 256;
                int m = u & 127, ch = u >> 7;
                *(half8*)&lsA[u * 8]  = *(const half8*)&A[(row0 + m) * 128 + kc * 32 + ch * 8];
                *(half8*)&lsBh[u * 8] = *(const half8*)&Bh[(size_t)m * 128 + kc * 32 + ch * 8];
                *(half8*)&lsBl[u * 8] = *(const half8*)&Bl[(size_t)m * 128 + kc * 32 + ch * 8];
            }
            __syncthreads();
            #pragma unroll
            for (int c = 0; c < 2; ++c) {
                const int base = (2 * c + lh) * 128;
                half8 a0  = *(half8*)&lsA[(base + mbase + lm) * 8];
                half8 a1  = *(half8*)&lsA[(base + mbase + 32 + lm) * 8];
                half8 bh0 = *(half8*)&lsBh[(base + nbase + lm) * 8];
                half8 bh1 = *(half8*)&lsBh[(base + nbase + 32 + lm) * 8];
                half8 bl0 = *(half8*)&lsBl[(base + nbase + lm) * 8];
                half8 bl1 = *(half8*)&lsBl[(base + nbase + 32 + lm) * 8];
                acc[0][0] = __builtin_amdgcn_mfma_f32_32x32x16_f16(a0, bh0, acc[0][0], 0, 0, 0);
                acc[0][0] = __builtin_amdgcn_mfma_f32_32x32x16_f16(a0, bl0, acc[0][0], 0, 0, 0);
                acc[0][1] = __builtin_amdgcn_mfma_f32_32x32x16_f16(a0, bh1, acc[0][1], 0, 0, 0);
                acc[0][1] = __builtin_amdgcn_mfma_f32_32x32x16_f16(a0, bl1, acc[0][1], 0, 0, 0);
                acc[1][0] = __builtin_amdgcn_mfma_f32_32x32x16_f16(a1, bh0, acc[1][0], 0, 0, 0);
                acc[1][0] = __builtin_amdgcn_mfma_f32_32x32x16_f16(a1, bl0, acc[1][0], 0, 0, 0);
                acc[1][1] = __builtin_amdgcn_mfma_f32_32x32x16_f16(a1, bh1, acc[1][1], 0, 0, 0);
                acc[1][1] = __builtin_amdgcn_mfma_f32_32x32x16_f16(a1, bl1, acc[1][1], 0, 0, 0);
            }
        }
    }
    #pragma unroll
    for (int ni = 0; ni < 2; ++ni) {
        int col = nbase + ni * 32 + lm;
        float bcol = bias[col];
        float s = 0.f, q = 0.f;
        #pragma unroll
        for (int mi = 0; mi < 2; ++mi) {
            #pragma unroll
            for (int r = 0; r < 16; ++r) {
                int row = mbase + mi * 32 + (r & 3) + 8 * (r >> 2) + 4 * lh;
                float o = acc[mi][ni][r] + bcol;
                outp[(row0 + row) * 128 + col] = (h16)o;
                s += o; q += o * o;
            }
        }
        atomicAdd(&csum[col], s);
        atomicAdd(&csq[col], q);
    }
    __syncthreads();
    if (tid < 128) atomicAdd(&gsum[tid], csum[tid]);
    else           atomicAdd(&gsq[tid - 128], csq[tid - 128]);
}

// ================= x = relu(BN1(h1)+BN2(h2)); fused BN-finalize + next submean =================
__global__ __launch_bounds__(256) void k_update(
    const h16* __restrict__ hpre, const h16* __restrict__ h2pre,
    const float* __restrict__ stats,
    const float* __restrict__ g1, const float* __restrict__ be1,
    const float* __restrict__ g2, const float* __restrict__ be2,
    h16* __restrict__ x, h16* __restrict__ subh)
{
    __shared__ float sA[128], hA[128], sB[128], hB[128];
    __shared__ float red[8][132];
    int gs = blockIdx.x, g = gs >> 5, tid = threadIdx.x;
    if (tid < 128) {
        float mu = stats[tid] * (1.f / T_);
        float var = stats[128 + tid] * (1.f / T_) - mu * mu;
        float sc = g1[tid] * rsqrtf(var + 1e-5f);
        sA[tid] = sc; hA[tid] = be1[tid] - mu * sc;
    } else {
        int c = tid - 128;
        float mu = stats[256 + c] * (1.f / TO_);
        float var = stats[384 + c] * (1.f / TO_) - mu * mu;
        float sc = g2[c] * rsqrtf(var + 1e-5f);
        sB[c] = sc; hB[c] = be2[c] - mu * sc;
    }
    __syncthreads();
    int cg = tid & 31, ng = tid >> 5;
    int c4 = cg * 4;
    float4 ssum = make_float4(0.f, 0.f, 0.f, 0.f);
    for (int n = ng; n < 32; n += 8) {
        size_t t = (size_t)gs * 32 + n;
        half4 h1v = *(const half4*)&hpre[t * 128 + c4];
        half4 h2v = *(const half4*)&h2pre[((size_t)g * 32 + n) * 128 + c4];
        float o0 = fmaxf((float)h1v[0] * sA[c4+0] + hA[c4+0] + (float)h2v[0] * sB[c4+0] + hB[c4+0], 0.f);
        float o1 = fmaxf((float)h1v[1] * sA[c4+1] + hA[c4+1] + (float)h2v[1] * sB[c4+1] + hB[c4+1], 0.f);
        float o2 = fmaxf((float)h1v[2] * sA[c4+2] + hA[c4+2] + (float)h2v[2] * sB[c4+2] + hB[c4+2], 0.f);
        float o3 = fmaxf((float)h1v[3] * sA[c4+3] + hA[c4+3] + (float)h2v[3] * sB[c4+3] + hB[c4+3], 0.f);
        half4 o; o[0] = (h16)o0; o[1] = (h16)o1; o[2] = (h16)o2; o[3] = (h16)o3;
        *(half4*)&x[t * 128 + c4] = o;
        ssum.x += o0; ssum.y += o1; ssum.z += o2; ssum.w += o3;
    }
    *(float4*)&red[ng][c4] = ssum;
    __syncthreads();
    if (ng == 0) {
        float4 s = make_float4(0.f, 0.f, 0.f, 0.f);
        #pragma unroll
        for (int r = 0; r < 8; ++r) {
            float4 v = *(float4*)&red[r][c4];
            s.x += v.x; s.y += v.y; s.z += v.z; s.w += v.w;
        }
        const float inv = 1.f / 32.f;
        half4 o; o[0] = (h16)(s.x*inv); o[1] = (h16)(s.y*inv); o[2] = (h16)(s.z*inv); o[3] = (h16)(s.w*inv);
        *(half4*)&subh[(size_t)gs * 128 + c4] = o;
    }
}

// ================= final head =================
__global__ __launch_bounds__(256) void k_dense(const h16* __restrict__ subh, const float* __restrict__ Wf1,
    const float* __restrict__ bf1, const float* __restrict__ Wf2, const float* __restrict__ bf2,
    float* __restrict__ out)
{
    int g = blockIdx.x, tid = threadIdx.x;
    __shared__ float hgs[128];
    __shared__ float hid[256];
    if (tid < 128) {
        float s = 0.f;
        for (int ss = 0; ss < 32; ++ss) s += (float)subh[((size_t)g * 32 + ss) * 128 + tid];
        hgs[tid] = s * (1.f / 32.f);
    }
    __syncthreads();
    float a = bf1[tid];
    for (int k = 0; k < 128; ++k) a += hgs[k] * Wf1[k * 256 + tid];
    hid[tid] = fmaxf(a, 0.f);
    __syncthreads();
    if (tid < 10) {
        float o = bf2[tid];
        for (int k = 0; k < 256; ++k) o += hid[k] * Wf2[k * 10 + tid];
        out[g * 10 + tid] = o;
    }
}

extern "C" void kernel_launch(void* const* d_in, const int* in_sizes, int n_in,
                              void* d_out, int out_size, void* d_ws, size_t ws_size,
                              hipStream_t stream)
{
    (void)in_sizes; (void)n_in; (void)out_size; (void)ws_size;
    const float* x0  = (const float*)d_in[0];
    const int*   ei  = (const int*)d_in[1];
    const int*   oei = (const int*)d_in[2];
    const float* Wr1 = (const float*)d_in[3];
    const float* Wn1 = (const float*)d_in[4];
    const float* b1  = (const float*)d_in[5];
    const float* g1  = (const float*)d_in[6];
    const float* be1 = (const float*)d_in[7];
    const float* Wr2 = (const float*)d_in[8];
    const float* Wn2 = (const float*)d_in[9];
    const float* b2  = (const float*)d_in[10];
    const float* g2  = (const float*)d_in[11];
    const float* be2 = (const float*)d_in[12];
    const float* Wq  = (const float*)d_in[13];
    const float* bq  = (const float*)d_in[14];
    const float* Wk  = (const float*)d_in[15];
    const float* bk  = (const float*)d_in[16];
    const float* Wf1 = (const float*)d_in[17];
    const float* bf1 = (const float*)d_in[18];
    const float* Wf2 = (const float*)d_in[19];
    const float* bf2 = (const float*)d_in[20];
    float* out = (float*)d_out;

    char* w = (char*)d_ws;
    size_t off = 0;
    auto alloc = [&](size_t bytes) { void* p = w + off; off = (off + bytes + 255) & ~(size_t)255; return p; };
    h16* xh     = (h16*)alloc((size_t)T_ * D_ * 2);
    h16* aggh   = (h16*)alloc((size_t)T_ * D_ * 2);   // aliased as h1pre (block-local RAW safe)
    h16* agg2   = (h16*)alloc((size_t)TO_ * D_ * 2);  // aliased as h2pre
    h16* xat    = (h16*)alloc((size_t)TO_ * D_ * 2);
    h16* wt     = (h16*)alloc((size_t)12 * 32768 * 2);
    h16* wqkt   = (h16*)alloc((size_t)6 * 16384 * 2);
    h16* subh   = (h16*)alloc((size_t)G_ * S_ * D_ * 2);
    // zero-init region: cnt | ocnt | stats(3 layers x 512)
    int* cnt     = (int*)alloc((size_t)(T_ + TO_) * 4 + 1536 * 4);
    int* ocnt    = cnt + T_;
    float* stats = (float*)(cnt + T_ + TO_);
    int* colsrc  = (int*)alloc((size_t)T_ * CAP_ * 4);    // 16 MB buckets
    int* ocolsrc = (int*)alloc((size_t)TO_ * CAP_ * 4);

    h16* h1pre = aggh;
    h16* h2pre = agg2;

    hipMemsetAsync(cnt, 0, (size_t)(T_ + TO_) * 4 + 1536 * 4, stream);
    k_prep<<<12592, 256, 0, stream>>>(ei, oei, Wr1, Wn1, Wr2, Wn2, Wq, Wk, x0,
                                      cnt, ocnt, colsrc, ocolsrc, wt, wqkt, xh, subh);

    for (int i = 0; i < 3; ++i) {
        k_agg2<<<dim3(T_ / 32, 2), 256, 0, stream>>>(xh, cnt, colsrc, aggh);
        k_attn<<<G_, 256, 0, stream>>>(subh, wqkt + (size_t)i * 2 * 16384,
            bq + i * D_, bk + i * D_, xh,
            (i == 2) ? (out + G_ * NTASK_) : nullptr, xat);
        k_aggo<<<TO_ / 8, 256, 0, stream>>>(xat, ocnt, ocolsrc, agg2);
        k_convs<<<1056, 256, 0, stream>>>(xh, aggh, xat, agg2, wt, i,
            b1 + i * D_, b2 + i * D_, h1pre, h2pre, stats + i * 512);
        k_update<<<G_ * S_, 256, 0, stream>>>(h1pre, h2pre, stats + i * 512,
            g1 + i * D_, be1 + i * D_, g2 + i * D_, be2 + i * D_, xh, subh);
    }
    k_dense<<<G_, 256, 0, stream>>>(subh, Wf1, bf1, Wf2, bf2, out);
}

// Round 7
// 650.970 us; speedup vs baseline: 4.0459x; 1.0083x over previous
//
#include <hip/hip_runtime.h>

#define G_   128
#define S_   32
#define N_   32
#define D_   128
#define T_   (G_*S_*N_)    // 131072
#define TO_  (G_*N_)       // 4096
#define E_   1048576
#define EO_  16384
#define NTASK_ 10
#define CAP_ 32            // bucket capacity per node (Poisson(8): P(deg>32) ~ 1e-11)

typedef _Float16 h16;
typedef _Float16 half8 __attribute__((ext_vector_type(8)));
typedef _Float16 half4 __attribute__((ext_vector_type(4)));
typedef float f32x16 __attribute__((ext_vector_type(16)));

// ================= merged setup =================
// grid: [0,8192)        bucketed fill of T edges; partition p = b&7 (XCD-affine), chunk = b>>3
//       [8192,8208)     bucketed fill of EO edges (16 blocks)
//       [8208,8400)     conv-weight split-fp16 transpose prep (12 mats x 16 chunks)
//       [8400,8496)     q/k fp16 transpose prep (6 x 16)
//       [8496,12592)    x0 -> fp16 + initial subgraph mean (4096 blocks)
__global__ __launch_bounds__(256) void k_prep(
    const int* __restrict__ ei, const int* __restrict__ oei,
    const float* __restrict__ Wr1, const float* __restrict__ Wn1,
    const float* __restrict__ Wr2, const float* __restrict__ Wn2,
    const float* __restrict__ Wq, const float* __restrict__ Wk,
    const float* __restrict__ x0,
    int* __restrict__ cnt, int* __restrict__ ocnt,
    int* __restrict__ colsrc, int* __restrict__ ocolsrc,
    h16* __restrict__ wt, h16* __restrict__ wqkt,
    h16* __restrict__ xh, h16* __restrict__ subh)
{
    __shared__ float red[8][132];
    int b = blockIdx.x, t = threadIdx.x;
    if (b < 8192) {
        // partition p handled ONLY by blocks with b&7==p -> (heuristically) one XCD,
        // so bucket-region partial lines stay in one L2 and write back once.
        const int p = b & 7;
        const int e0 = (b >> 3) * 1024 + t * 4;
        const int4 d4 = *(const int4*)&ei[E_ + e0];
        const int4 s4 = *(const int4*)&ei[e0];
        #pragma unroll
        for (int j = 0; j < 4; ++j) {
            int d = (&d4.x)[j];
            if ((d >> 14) == p) {
                int pos = atomicAdd(&cnt[d], 1);
                if (pos < CAP_) colsrc[(d << 5) + pos] = (&s4.x)[j];
            }
        }
    } else if (b < 8208) {
        const int e0 = (b - 8192) * 1024 + t * 4;
        const int4 d4 = *(const int4*)&oei[EO_ + e0];
        const int4 s4 = *(const int4*)&oei[e0];
        #pragma unroll
        for (int j = 0; j < 4; ++j) {
            int d = (&d4.x)[j];
            int pos = atomicAdd(&ocnt[d], 1);
            if (pos < CAP_) ocolsrc[(d << 5) + pos] = (&s4.x)[j];
        }
    } else if (b < 8400) {
        int idx = b - 8208, mat = idx >> 4, chunk = idx & 15;
        int arr = mat / 3, layer = mat % 3;
        const float* W = (arr == 0 ? Wr1 : arr == 1 ? Wn1 : arr == 2 ? Wr2 : Wn2) + (size_t)layer * 16384;
        h16* outh = wt + (size_t)mat * 32768;
        h16* outl = outh + 16384;
        int base = chunk * 1024;
        for (int i = t; i < 1024; i += 256) {
            int id = base + i;
            int k = id >> 7, n = id & 127;
            float v = W[id];
            h16 hi = (h16)v;
            h16 lo = (h16)(v - (float)hi);
            outh[n * 128 + k] = hi;
            outl[n * 128 + k] = lo;
        }
    } else if (b < 8496) {
        int idx = b - 8400, m = idx >> 4, chunk = idx & 15;
        int layer = m >> 1, which = m & 1;
        const float* W = (which ? Wk : Wq) + (size_t)layer * 16384;
        h16* o = wqkt + (size_t)m * 16384;
        int base = chunk * 1024;
        for (int i = t; i < 1024; i += 256) {
            int id = base + i;
            int k = id >> 7, n = id & 127;
            o[n * 128 + k] = (h16)W[id];
        }
    } else {
        int gs = b - 8496;
        int cg = t & 31, rg = t >> 5;
        int c4 = cg * 4;
        float4 ssum = make_float4(0.f, 0.f, 0.f, 0.f);
        for (int n = rg; n < 32; n += 8) {
            size_t tt = (size_t)gs * 32 + n;
            float4 v = *(const float4*)&x0[tt * 128 + c4];
            half4 o; o[0] = (h16)v.x; o[1] = (h16)v.y; o[2] = (h16)v.z; o[3] = (h16)v.w;
            *(half4*)&xh[tt * 128 + c4] = o;
            ssum.x += v.x; ssum.y += v.y; ssum.z += v.z; ssum.w += v.w;
        }
        *(float4*)&red[rg][c4] = ssum;
        __syncthreads();
        if (rg == 0) {
            float4 s = make_float4(0.f, 0.f, 0.f, 0.f);
            #pragma unroll
            for (int r = 0; r < 8; ++r) {
                float4 v = *(float4*)&red[r][c4];
                s.x += v.x; s.y += v.y; s.z += v.z; s.w += v.w;
            }
            const float inv = 1.f / 32.f;
            half4 o; o[0] = (h16)(s.x*inv); o[1] = (h16)(s.y*inv); o[2] = (h16)(s.z*inv); o[3] = (h16)(s.w*inv);
            *(half4*)&subh[(size_t)gs * 128 + c4] = o;
        }
    }
}

// ================= bucketed CSR aggregation, 2 feature-plane passes (grid.y) =================
__global__ __launch_bounds__(256) void k_agg2(
    const h16* __restrict__ xh, const int* __restrict__ cnt, const int* __restrict__ colsrc,
    h16* __restrict__ agg)
{
    const int nid = blockIdx.x * 32 + (threadIdx.x >> 3);
    const int foff = blockIdx.y * 64 + (threadIdx.x & 7) * 8;
    int n = cnt[nid]; n = (n > CAP_) ? CAP_ : n;
    const int* __restrict__ bucket = colsrc + ((size_t)nid << 5);
    float acc[8] = {0.f,0.f,0.f,0.f,0.f,0.f,0.f,0.f};
    for (int e = 0; e < n; e += 4) {
        int4 s4 = *(const int4*)&bucket[e];
        #pragma unroll
        for (int j = 0; j < 4; ++j) {
            bool ok = (e + j) < n;
            int s = ok ? (&s4.x)[j] : 0;
            half8 v = *(const half8*)&xh[(size_t)s * 128 + foff];
            if (ok) {
                #pragma unroll
                for (int q = 0; q < 8; ++q) acc[q] += (float)v[q];
            }
        }
    }
    half8 o;
    #pragma unroll
    for (int j = 0; j < 8; ++j) o[j] = (h16)acc[j];
    *(half8*)&agg[(size_t)nid * 128 + foff] = o;
}

// ================= per-graph attention: q/k MFMA -> softmax -> head-mean -> x_atten =================
__global__ __launch_bounds__(256) void k_attn(
    const h16* __restrict__ subh, const h16* __restrict__ wqkt_l,
    const float* __restrict__ bql, const float* __restrict__ bkl,
    const h16* __restrict__ xh, float* __restrict__ heat, h16* __restrict__ xat)
{
    __shared__ __align__(16) char smem[25600];
    const int tid = threadIdx.x;
    const int g = blockIdx.x;
    h16* aF = (h16*)smem;                   // 512 frag units x 8 h16 = 8KB
    h16* qkT = (h16*)(smem + 8192);         // [mat][n(128)][34] fp16
    float* attn_s = (float*)smem;           // alias over aF after GEMM phase
    #pragma unroll
    for (int it = 0; it < 2; ++it) {
        int u = tid + it * 256;
        int kq = u >> 6, l = u & 63;
        int m = l & 31, ko = kq * 16 + (l >> 5) * 8;
        *(half8*)&aF[u * 8] = *(const half8*)&subh[((size_t)g * 32 + m) * 128 + ko];
    }
    __syncthreads();
    const int w = tid >> 6, lane = tid & 63, lm = lane & 31, lh = lane >> 5;
    const int mat = w & 1, ntp = (w >> 1) * 2;
    const h16* Wt = wqkt_l + (size_t)mat * 16384;
    const float* bias = mat ? bkl : bql;
    f32x16 a0, a1;
    #pragma unroll
    for (int r = 0; r < 16; ++r) { a0[r] = 0.f; a1[r] = 0.f; }
    #pragma unroll
    for (int kq = 0; kq < 8; ++kq) {
        half8 av = *(half8*)&aF[(kq * 64 + lane) * 8];
        half8 b0 = *(const half8*)&Wt[(size_t)(ntp * 32 + lm) * 128 + kq * 16 + lh * 8];
        half8 b1 = *(const half8*)&Wt[(size_t)((ntp + 1) * 32 + lm) * 128 + kq * 16 + lh * 8];
        a0 = __builtin_amdgcn_mfma_f32_32x32x16_f16(av, b0, a0, 0, 0, 0);
        a1 = __builtin_amdgcn_mfma_f32_32x32x16_f16(av, b1, a1, 0, 0, 0);
    }
    __syncthreads();
    #pragma unroll
    for (int ti = 0; ti < 2; ++ti) {
        int n = (ntp + ti) * 32 + lm;
        float bn = bias[n];
        #pragma unroll
        for (int r = 0; r < 16; ++r) {
            int s = (r & 3) + 8 * (r >> 2) + 4 * lh;
            float v = (ti ? a1[r] : a0[r]) + bn;
            qkT[(mat * 128 + n) * 34 + s] = (h16)v;
        }
    }
    for (int i = tid; i < 1024; i += 256) attn_s[i] = 0.f;
    __syncthreads();
    if (tid < 128) {
        int h = tid >> 5, i = tid & 31;
        float qreg[32];
        #pragma unroll
        for (int d = 0; d < 32; ++d) qreg[d] = (float)qkT[(h * 32 + d) * 34 + i];
        float sc[32];
        const float scale = 0.17677669529663687f; // 1/sqrt(32)
        float mx = -1e30f;
        #pragma unroll
        for (int j = 0; j < 32; ++j) {
            float d = 0.f;
            #pragma unroll
            for (int d0 = 0; d0 < 32; ++d0) d += qreg[d0] * (float)qkT[(128 + h * 32 + d0) * 34 + j];
            d *= scale;
            sc[j] = d;
            mx = fmaxf(mx, d);
        }
        float ssum = 0.f;
        #pragma unroll
        for (int j = 0; j < 32; ++j) { float ee = __expf(sc[j] - mx); sc[j] = ee; ssum += ee; }
        float inv = 0.25f / ssum;  // head-mean folded in
        #pragma unroll
        for (int j = 0; j < 32; ++j) atomicAdd(&attn_s[i * 32 + j], sc[j] * inv);
    }
    __syncthreads();
    if (heat != nullptr && g == 127) {
        for (int idx = tid; idx < 1024; idx += 256) heat[idx] = attn_s[idx];
    }
    {
        int c4 = (tid & 31) * 4;
        int ng = tid >> 5;
        for (int n = ng; n < 32; n += 8) {
            float ax = 0.f, ay = 0.f, az = 0.f, aw = 0.f;
            #pragma unroll
            for (int s = 0; s < 32; ++s) {
                float a = attn_s[s * 32 + n];
                half4 xv = *(const half4*)&xh[(((size_t)g * 32 + s) * 32 + n) * 128 + c4];
                ax += a * (float)xv[0]; ay += a * (float)xv[1];
                az += a * (float)xv[2]; aw += a * (float)xv[3];
            }
            half4 o; o[0] = (h16)ax; o[1] = (h16)ay; o[2] = (h16)az; o[3] = (h16)aw;
            *(half4*)&xat[((size_t)g * 32 + n) * 128 + c4] = o;
        }
    }
}

// ================= bucketed aggregation for original graph (small, L2-resident) =================
__global__ __launch_bounds__(256) void k_aggo(
    const h16* __restrict__ x, const int* __restrict__ ocnt, const int* __restrict__ ocolsrc,
    h16* __restrict__ agg)
{
    int nid = blockIdx.x * 8 + (threadIdx.x >> 5);
    int lane = threadIdx.x & 31;
    int n = ocnt[nid]; n = (n > CAP_) ? CAP_ : n;
    const int* __restrict__ bucket = ocolsrc + ((size_t)nid << 5);
    float ax = 0.f, ay = 0.f, az = 0.f, aw = 0.f;
    for (int e = 0; e < n; e += 4) {
        int4 s4 = *(const int4*)&bucket[e];
        #pragma unroll
        for (int j = 0; j < 4; ++j) {
            bool ok = (e + j) < n;
            int s = ok ? (&s4.x)[j] : 0;
            half4 v = *(const half4*)&x[(size_t)s * 128 + lane * 4];
            if (ok) { ax += (float)v[0]; ay += (float)v[1]; az += (float)v[2]; aw += (float)v[3]; }
        }
    }
    half4 o; o[0] = (h16)ax; o[1] = (h16)ay; o[2] = (h16)az; o[3] = (h16)aw;
    *(half4*)&agg[(size_t)nid * 128 + lane * 4] = o;
}

// ================= merged MFMA GraphConv (T branch | TO branch) + BN stats =================
__global__ __launch_bounds__(256) void k_convs(
    const h16* __restrict__ xT, const h16* __restrict__ aggT,
    const h16* __restrict__ xO, const h16* __restrict__ aggO,
    const h16* __restrict__ wt, int layer,
    const float* __restrict__ b1l, const float* __restrict__ b2l,
    h16* __restrict__ h1, h16* __restrict__ h2, float* __restrict__ stats)
{
    __shared__ h16 lsA[4096];
    __shared__ h16 lsBh[4096];
    __shared__ h16 lsBl[4096];
    __shared__ float csum[128], csq[128];
    const int tid = threadIdx.x;
    const h16 *A0, *A1, *W0, *W1; const float* bias; h16* outp; float *gsum, *gsq; size_t row0;
    if (blockIdx.x < 1024) {
        A0 = xT; A1 = aggT;
        W0 = wt + (size_t)(0 * 3 + layer) * 32768;
        W1 = wt + (size_t)(1 * 3 + layer) * 32768;
        bias = b1l; outp = h1; gsum = stats; gsq = stats + 128;
        row0 = (size_t)blockIdx.x * 128;
    } else {
        A0 = xO; A1 = aggO;
        W0 = wt + (size_t)(2 * 3 + layer) * 32768;
        W1 = wt + (size_t)(3 * 3 + layer) * 32768;
        bias = b2l; outp = h2; gsum = stats + 256; gsq = stats + 384;
        row0 = (size_t)(blockIdx.x - 1024) * 128;
    }
    if (tid < 128) { csum[tid] = 0.f; csq[tid] = 0.f; }
    const int w = tid >> 6, lane = tid & 63, lm = lane & 31, lh = lane >> 5;
    const int mbase = (w & 1) * 64, nbase = (w >> 1) * 64;
    f32x16 acc[2][2];
    #pragma unroll
    for (int mi = 0; mi < 2; ++mi)
        #pragma unroll
        for (int ni = 0; ni < 2; ++ni)
            #pragma unroll
            for (int r = 0; r < 16; ++r) acc[mi][ni][r] = 0.f;

    for (int p = 0; p < 2; ++p) {
        const h16* A  = p ? A1 : A0;
        const h16* Bh = p ? W1 : W0;
        const h16* Bl = Bh + 16384;
        for (int kc = 0; kc < 4; ++kc) {
            __syncthreads();
            #pragma unroll
            for (int it = 0; it < 2; ++it) {
                int u = tid + it * 256;
                int m = u & 127, ch = u >> 7;
                *(half8*)&lsA[u * 8]  = *(const half8*)&A[(row0 + m) * 128 + kc * 32 + ch * 8];
                *(half8*)&lsBh[u * 8] = *(const half8*)&Bh[(size_t)m * 128 + kc * 32 + ch * 8];
                *(half8*)&lsBl[u * 8] = *(const half8*)&Bl[(size_t)m * 128 + kc * 32 + ch * 8];
            }
            __syncthreads();
            #pragma unroll
            for (int c = 0; c < 2; ++c) {
                const int base = (2 * c + lh) * 128;
                half8 a0  = *(half8*)&lsA[(base + mbase + lm) * 8];
                half8 a1  = *(half8*)&lsA[(base + mbase + 32 + lm) * 8];
                half8 bh0 = *(half8*)&lsBh[(base + nbase + lm) * 8];
                half8 bh1 = *(half8*)&lsBh[(base + nbase + 32 + lm) * 8];
                half8 bl0 = *(half8*)&lsBl[(base + nbase + lm) * 8];
                half8 bl1 = *(half8*)&lsBl[(base + nbase + 32 + lm) * 8];
                acc[0][0] = __builtin_amdgcn_mfma_f32_32x32x16_f16(a0, bh0, acc[0][0], 0, 0, 0);
                acc[0][0] = __builtin_amdgcn_mfma_f32_32x32x16_f16(a0, bl0, acc[0][0], 0, 0, 0);
                acc[0][1] = __builtin_amdgcn_mfma_f32_32x32x16_f16(a0, bh1, acc[0][1], 0, 0, 0);
                acc[0][1] = __builtin_amdgcn_mfma_f32_32x32x16_f16(a0, bl1, acc[0][1], 0, 0, 0);
                acc[1][0] = __builtin_amdgcn_mfma_f32_32x32x16_f16(a1, bh0, acc[1][0], 0, 0, 0);
                acc[1][0] = __builtin_amdgcn_mfma_f32_32x32x16_f16(a1, bl0, acc[1][0], 0, 0, 0);
                acc[1][1] = __builtin_amdgcn_mfma_f32_32x32x16_f16(a1, bh1, acc[1][1], 0, 0, 0);
                acc[1][1] = __builtin_amdgcn_mfma_f32_32x32x16_f16(a1, bl1, acc[1][1], 0, 0, 0);
            }
        }
    }
    #pragma unroll
    for (int ni = 0; ni < 2; ++ni) {
        int col = nbase + ni * 32 + lm;
        float bcol = bias[col];
        float s = 0.f, q = 0.f;
        #pragma unroll
        for (int mi = 0; mi < 2; ++mi) {
            #pragma unroll
            for (int r = 0; r < 16; ++r) {
                int row = mbase + mi * 32 + (r & 3) + 8 * (r >> 2) + 4 * lh;
                float o = acc[mi][ni][r] + bcol;
                outp[(row0 + row) * 128 + col] = (h16)o;
                s += o; q += o * o;
            }
        }
        atomicAdd(&csum[col], s);
        atomicAdd(&csq[col], q);
    }
    __syncthreads();
    if (tid < 128) atomicAdd(&gsum[tid], csum[tid]);
    else           atomicAdd(&gsq[tid - 128], csq[tid - 128]);
}

// ================= x = relu(BN1(h1)+BN2(h2)); fused BN-finalize + next submean =================
__global__ __launch_bounds__(256) void k_update(
    const h16* __restrict__ hpre, const h16* __restrict__ h2pre,
    const float* __restrict__ stats,
    const float* __restrict__ g1, const float* __restrict__ be1,
    const float* __restrict__ g2, const float* __restrict__ be2,
    h16* __restrict__ x, h16* __restrict__ subh)
{
    __shared__ float sA[128], hA[128], sB[128], hB[128];
    __shared__ float red[8][132];
    int gs = blockIdx.x, g = gs >> 5, tid = threadIdx.x;
    if (tid < 128) {
        float mu = stats[tid] * (1.f / T_);
        float var = stats[128 + tid] * (1.f / T_) - mu * mu;
        float sc = g1[tid] * rsqrtf(var + 1e-5f);
        sA[tid] = sc; hA[tid] = be1[tid] - mu * sc;
    } else {
        int c = tid - 128;
        float mu = stats[256 + c] * (1.f / TO_);
        float var = stats[384 + c] * (1.f / TO_) - mu * mu;
        float sc = g2[c] * rsqrtf(var + 1e-5f);
        sB[c] = sc; hB[c] = be2[c] - mu * sc;
    }
    __syncthreads();
    int cg = tid & 31, ng = tid >> 5;
    int c4 = cg * 4;
    float4 ssum = make_float4(0.f, 0.f, 0.f, 0.f);
    for (int n = ng; n < 32; n += 8) {
        size_t t = (size_t)gs * 32 + n;
        half4 h1v = *(const half4*)&hpre[t * 128 + c4];
        half4 h2v = *(const half4*)&h2pre[((size_t)g * 32 + n) * 128 + c4];
        float o0 = fmaxf((float)h1v[0] * sA[c4+0] + hA[c4+0] + (float)h2v[0] * sB[c4+0] + hB[c4+0], 0.f);
        float o1 = fmaxf((float)h1v[1] * sA[c4+1] + hA[c4+1] + (float)h2v[1] * sB[c4+1] + hB[c4+1], 0.f);
        float o2 = fmaxf((float)h1v[2] * sA[c4+2] + hA[c4+2] + (float)h2v[2] * sB[c4+2] + hB[c4+2], 0.f);
        float o3 = fmaxf((float)h1v[3] * sA[c4+3] + hA[c4+3] + (float)h2v[3] * sB[c4+3] + hB[c4+3], 0.f);
        half4 o; o[0] = (h16)o0; o[1] = (h16)o1; o[2] = (h16)o2; o[3] = (h16)o3;
        *(half4*)&x[t * 128 + c4] = o;
        ssum.x += o0; ssum.y += o1; ssum.z += o2; ssum.w += o3;
    }
    *(float4*)&red[ng][c4] = ssum;
    __syncthreads();
    if (ng == 0) {
        float4 s = make_float4(0.f, 0.f, 0.f, 0.f);
        #pragma unroll
        for (int r = 0; r < 8; ++r) {
            float4 v = *(float4*)&red[r][c4];
            s.x += v.x; s.y += v.y; s.z += v.z; s.w += v.w;
        }
        const float inv = 1.f / 32.f;
        half4 o; o[0] = (h16)(s.x*inv); o[1] = (h16)(s.y*inv); o[2] = (h16)(s.z*inv); o[3] = (h16)(s.w*inv);
        *(half4*)&subh[(size_t)gs * 128 + c4] = o;
    }
}

// ================= final head =================
__global__ __launch_bounds__(256) void k_dense(const h16* __restrict__ subh, const float* __restrict__ Wf1,
    const float* __restrict__ bf1, const float* __restrict__ Wf2, const float* __restrict__ bf2,
    float* __restrict__ out)
{
    int g = blockIdx.x, tid = threadIdx.x;
    __shared__ float hgs[128];
    __shared__ float hid[256];
    if (tid < 128) {
        float s = 0.f;
        for (int ss = 0; ss < 32; ++ss) s += (float)subh[((size_t)g * 32 + ss) * 128 + tid];
        hgs[tid] = s * (1.f / 32.f);
    }
    __syncthreads();
    float a = bf1[tid];
    for (int k = 0; k < 128; ++k) a += hgs[k] * Wf1[k * 256 + tid];
    hid[tid] = fmaxf(a, 0.f);
    __syncthreads();
    if (tid < 10) {
        float o = bf2[tid];
        for (int k = 0; k < 256; ++k) o += hid[k] * Wf2[k * 10 + tid];
        out[g * 10 + tid] = o;
    }
}

extern "C" void kernel_launch(void* const* d_in, const int* in_sizes, int n_in,
                              void* d_out, int out_size, void* d_ws, size_t ws_size,
                              hipStream_t stream)
{
    (void)in_sizes; (void)n_in; (void)out_size; (void)ws_size;
    const float* x0  = (const float*)d_in[0];
    const int*   ei  = (const int*)d_in[1];
    const int*   oei = (const int*)d_in[2];
    const float* Wr1 = (const float*)d_in[3];
    const float* Wn1 = (const float*)d_in[4];
    const float* b1  = (const float*)d_in[5];
    const float* g1  = (const float*)d_in[6];
    const float* be1 = (const float*)d_in[7];
    const float* Wr2 = (const float*)d_in[8];
    const float* Wn2 = (const float*)d_in[9];
    const float* b2  = (const float*)d_in[10];
    const float* g2  = (const float*)d_in[11];
    const float* be2 = (const float*)d_in[12];
    const float* Wq  = (const float*)d_in[13];
    const float* bq  = (const float*)d_in[14];
    const float* Wk  = (const float*)d_in[15];
    const float* bk  = (const float*)d_in[16];
    const float* Wf1 = (const float*)d_in[17];
    const float* bf1 = (const float*)d_in[18];
    const float* Wf2 = (const float*)d_in[19];
    const float* bf2 = (const float*)d_in[20];
    float* out = (float*)d_out;

    char* w = (char*)d_ws;
    size_t off = 0;
    auto alloc = [&](size_t bytes) { void* p = w + off; off = (off + bytes + 255) & ~(size_t)255; return p; };
    h16* xh     = (h16*)alloc((size_t)T_ * D_ * 2);
    h16* aggh   = (h16*)alloc((size_t)T_ * D_ * 2);   // aliased as h1pre (block-local RAW safe)
    h16* agg2   = (h16*)alloc((size_t)TO_ * D_ * 2);  // aliased as h2pre
    h16* xat    = (h16*)alloc((size_t)TO_ * D_ * 2);
    h16* wt     = (h16*)alloc((size_t)12 * 32768 * 2);
    h16* wqkt   = (h16*)alloc((size_t)6 * 16384 * 2);
    h16* subh   = (h16*)alloc((size_t)G_ * S_ * D_ * 2);
    // zero-init region: cnt | ocnt | stats(3 layers x 512)
    int* cnt     = (int*)alloc((size_t)(T_ + TO_) * 4 + 1536 * 4);
    int* ocnt    = cnt + T_;
    float* stats = (float*)(cnt + T_ + TO_);
    int* colsrc  = (int*)alloc((size_t)T_ * CAP_ * 4);    // 16 MB buckets
    int* ocolsrc = (int*)alloc((size_t)TO_ * CAP_ * 4);

    h16* h1pre = aggh;
    h16* h2pre = agg2;

    hipMemsetAsync(cnt, 0, (size_t)(T_ + TO_) * 4 + 1536 * 4, stream);
    k_prep<<<12592, 256, 0, stream>>>(ei, oei, Wr1, Wn1, Wr2, Wn2, Wq, Wk, x0,
                                      cnt, ocnt, colsrc, ocolsrc, wt, wqkt, xh, subh);

    for (int i = 0; i < 3; ++i) {
        k_agg2<<<dim3(T_ / 32, 2), 256, 0, stream>>>(xh, cnt, colsrc, aggh);
        k_attn<<<G_, 256, 0, stream>>>(subh, wqkt + (size_t)i * 2 * 16384,
            bq + i * D_, bk + i * D_, xh,
            (i == 2) ? (out + G_ * NTASK_) : nullptr, xat);
        k_aggo<<<TO_ / 8, 256, 0, stream>>>(xat, ocnt, ocolsrc, agg2);
        k_convs<<<1056, 256, 0, stream>>>(xh, aggh, xat, agg2, wt, i,
            b1 + i * D_, b2 + i * D_, h1pre, h2pre, stats + i * 512);
        k_update<<<G_ * S_, 256, 0, stream>>>(h1pre, h2pre, stats + i * 512,
            g1 + i * D_, be1 + i * D_, g2 + i * D_, be2 + i * D_, xh, subh);
    }
    k_dense<<<G_, 256, 0, stream>>>(subh, Wf1, bf1, Wf2, bf2, out);
}